// Round 6
// baseline (1200.690 us; speedup 1.0000x reference)
//
#include <hip/hip_runtime.h>
#include <cstdint>

#define L_ 4
#define D_ 2048
#define H_ 16
#define KVH_ 8
#define DH_ 128
#define F_ 6144
#define V_ 32000
#define SMAX_ 2048
#define T_ 1024
#define EPS_ 1e-6f
#define QB 32
#define SB 128
#define ZSE 4194304  // elements between split-K partial planes (16 MB)

typedef unsigned short u16;
typedef unsigned int u32;
typedef float fvec4 __attribute__((ext_vector_type(4)));
typedef float f32x4 __attribute__((ext_vector_type(4)));
typedef __bf16 bf16x8 __attribute__((ext_vector_type(8)));

__device__ __forceinline__ u16 f2bf(float f) {
  union { float f; u32 u; } a; a.f = f;
  u32 u = a.u;
  return (u16)((u + 0x7FFFu + ((u >> 16) & 1u)) >> 16);
}

__device__ __forceinline__ void gld16(const void* g, void* l) {
  __builtin_amdgcn_global_load_lds(
      (const __attribute__((address_space(1))) void*)g,
      (__attribute__((address_space(3))) void*)l, 16, 0, 0);
}

__device__ __forceinline__ float blk_sum(float v, volatile float* sm) {
#pragma unroll
  for (int m = 32; m; m >>= 1) v += __shfl_xor(v, m);
  if ((threadIdx.x & 63) == 0) sm[threadIdx.x >> 6] = v;
  __syncthreads();
  v = sm[0] + sm[1] + sm[2] + sm[3];
  __syncthreads();
  return v;
}

// ---------------- embedding (uint8-vs-int32 runtime detection) ---------------
__global__ void embed_k(const int* __restrict__ ids, const void* __restrict__ edata,
                        const float* __restrict__ esc, const float* __restrict__ ez,
                        float* __restrict__ hidden)
{
  const int* ei = (const int*)edata;
  int chk = ei[threadIdx.x & 63];
  bool ok = ((unsigned)chk) <= 255u;
  bool is_i32 = (__ballot(ok) == ~0ULL);
  int t = blockIdx.x;
  int id = ids[t];
  float sc = esc[id], zp = ez[id];
  size_t base = (size_t)id * D_;
  const uint8_t* eb = (const uint8_t*)edata;
  for (int d = threadIdx.x; d < D_; d += 256) {
    float e = is_i32 ? (float)ei[base + d] : (float)eb[base + d];
    hidden[(size_t)t * D_ + d] = e * sc + zp;
  }
}

// ------ convT v2: up to 3 segments, fvec4 loads, [64][65] f32 LDS ------------
__global__ __launch_bounds__(256)
void convT2_k(const float* __restrict__ W0, const float* __restrict__ W1,
              const float* __restrict__ W2,
              int x1, int x2, int N0, int N1, int N2,
              int r0, int r1, int r2, int K, u16* __restrict__ WT, int gu)
{
  __shared__ float tile[64][65];
  int x = blockIdx.x, k0 = blockIdx.y * 64;
  const float* W; int N, nb, rb;
  if (x < x1)      { W = W0; N = N0; nb = x;      rb = r0; }
  else if (x < x2) { W = W1; N = N1; nb = x - x1; rb = r1; }
  else             { W = W2; N = N2; nb = x - x2; rb = r2; }
  int n0 = nb * 64;
  int tid = threadIdx.x;
  int lk = tid >> 4, n4 = (tid & 15) * 4;
#pragma unroll
  for (int i = 0; i < 4; ++i) {
    int kr = i * 16 + lk;
    fvec4 v = *(const fvec4*)(W + (size_t)(k0 + kr) * N + n0 + n4);
#pragma unroll
    for (int j = 0; j < 4; ++j) tile[n4 + j][kr] = v[j];
  }
  __syncthreads();
  int n = tid >> 2, kq = (tid & 3) * 16;
  int f = n0 + n;
  int row = gu ? (rb + ((f >> 4) << 5) + (f & 15)) : (rb + f);
  union { u16 h[16]; uint4 q[2]; } o;
#pragma unroll
  for (int i = 0; i < 16; ++i) o.h[i] = f2bf(tile[n][kq + i]);
  u16* op = WT + (size_t)row * K + k0 + kq;
  *(uint4*)op = o.q[0];
  *(uint4*)(op + 8) = o.q[1];
}

// ------ RMS norm f32 -> bf16; one wave per row; NZ: x += sum of NZ partials --
template<int NZ>
__global__ __launch_bounds__(256)
void rms_k(float* __restrict__ x, const float* __restrict__ p,
           const float* __restrict__ w, u16* __restrict__ out)
{
  int t = blockIdx.x * 4 + (threadIdx.x >> 6);
  int l = threadIdx.x & 63;
  fvec4* xr = (fvec4*)(x + (size_t)t * D_);
  fvec4 v[8];
#pragma unroll
  for (int j = 0; j < 8; ++j) v[j] = xr[l + 64 * j];
  if (NZ > 0) {
#pragma unroll
    for (int z = 0; z < NZ; ++z) {
      const fvec4* a = (const fvec4*)(p + (size_t)z * ZSE + (size_t)t * D_);
#pragma unroll
      for (int j = 0; j < 8; ++j) v[j] += a[l + 64 * j];
    }
#pragma unroll
    for (int j = 0; j < 8; ++j) xr[l + 64 * j] = v[j];
  }
  float s = 0.f;
#pragma unroll
  for (int j = 0; j < 8; ++j)
    s += v[j][0]*v[j][0] + v[j][1]*v[j][1] + v[j][2]*v[j][2] + v[j][3]*v[j][3];
#pragma unroll
  for (int m = 32; m; m >>= 1) s += __shfl_xor(s, m);
  float inv = rsqrtf(s * (1.f / D_) + EPS_);
  const fvec4* wr = (const fvec4*)w;
  u16* orow = out + (size_t)t * D_;
#pragma unroll
  for (int j = 0; j < 8; ++j) {
    fvec4 wv = wr[l + 64 * j];
    uint2 o;
    o.x = (u32)f2bf(wv[0]*v[j][0]*inv) | ((u32)f2bf(wv[1]*v[j][1]*inv) << 16);
    o.y = (u32)f2bf(wv[2]*v[j][2]*inv) | ((u32)f2bf(wv[3]*v[j][3]*inv) << 16);
    *(uint2*)(orow + (l + 64 * j) * 4) = o;
  }
}

// -------- GEMM: C(MxN)=A(MxK)*B^T(NxK) bf16, split-K via blockIdx.z ----------
// EPI 0: Cf[z]=acc (partial)  EPI 3: silu-pair -> Cb bf16
template<int EPI>
__global__ __launch_bounds__(256)
void gemm_bt(const u16* __restrict__ A, const u16* __restrict__ B,
             float* __restrict__ Cf, u16* __restrict__ Cb,
             int K, int Ks, int ldC, long long zStride)
{
  __shared__ u16 lA[128 * 64];
  __shared__ u16 lB[128 * 64];
  const u16* Ab = A + (size_t)blockIdx.y * 128 * K;
  const u16* Bb = B + (size_t)blockIdx.x * 128 * K;
  int kz = blockIdx.z * Ks;

  int tid = threadIdx.x;
  int l = tid & 63;
  int wid = tid >> 6;
  int wr = wid >> 1, wc = wid & 1;
  int lrow = l & 15, lk = l >> 4;

  f32x4 acc[4][4] = {};

  for (int k0 = 0; k0 < Ks; k0 += 64) {
#pragma unroll
    for (int r = 0; r < 4; ++r) {
      int c = r * 256 + tid;
      int row = c >> 3, g = c & 7;
      int kel = kz + k0 + ((g ^ (row & 7)) << 3);
      gld16(Ab + (size_t)row * K + kel, (char*)lA + c * 16);
      gld16(Bb + (size_t)row * K + kel, (char*)lB + c * 16);
    }
    __syncthreads();
#pragma unroll
    for (int kk = 0; kk < 2; ++kk) {
      bf16x8 av[4], bv[4];
      int kbyte = (kk * 32 + lk * 8) * 2;
#pragma unroll
      for (int m = 0; m < 4; ++m) {
        int row = wr * 64 + m * 16 + lrow;
        int byt = (row * 128 + kbyte) ^ ((row & 7) << 4);
        av[m] = *(const bf16x8*)((const char*)lA + byt);
      }
#pragma unroll
      for (int n = 0; n < 4; ++n) {
        int row = wc * 64 + n * 16 + lrow;
        int byt = (row * 128 + kbyte) ^ ((row & 7) << 4);
        bv[n] = *(const bf16x8*)((const char*)lB + byt);
      }
#pragma unroll
      for (int m = 0; m < 4; ++m)
#pragma unroll
        for (int n = 0; n < 4; ++n)
          acc[m][n] = __builtin_amdgcn_mfma_f32_16x16x32_bf16(av[m], bv[n], acc[m][n], 0, 0, 0);
    }
    __syncthreads();
  }

  int grow0 = blockIdx.y * 128 + wr * 64 + lk * 4;
  if (EPI == 3) {
    int fcol0 = blockIdx.x * 64 + wc * 32 + lrow;
#pragma unroll
    for (int m = 0; m < 4; ++m)
#pragma unroll
      for (int np = 0; np < 2; ++np)
#pragma unroll
        for (int r = 0; r < 4; ++r) {
          float g = acc[m][2 * np][r], u = acc[m][2 * np + 1][r];
          float val = g / (1.f + __expf(-g)) * u;
          Cb[(size_t)(grow0 + m * 16 + r) * ldC + fcol0 + np * 16] = f2bf(val);
        }
    return;
  }
  float* Cz = Cf + (long long)blockIdx.z * zStride;
  int gcol0 = blockIdx.x * 128 + wc * 64 + lrow;
#pragma unroll
  for (int m = 0; m < 4; ++m)
#pragma unroll
    for (int n = 0; n < 4; ++n)
#pragma unroll
      for (int r = 0; r < 4; ++r) {
        size_t off = (size_t)(grow0 + m * 16 + r) * ldC + gcol0 + n * 16;
        Cz[off] = acc[m][n][r];
      }
}

// ------------- fused QKV post-process: tiled, fully coalesced ----------------
// grid (T/64, 32): z<16 Q head z | z<24 K kv=z-16 (+key_out transpose) | V kv=z-24
__global__ __launch_bounds__(256)
void qkvpost_k(const float* __restrict__ p0, const float* __restrict__ p1,
               const float* __restrict__ wq, const float* __restrict__ wk,
               const float* __restrict__ cosT, const float* __restrict__ sinT,
               const int* __restrict__ plp,
               u16* __restrict__ qr, u16* __restrict__ kr, u16* __restrict__ vT,
               float* __restrict__ key_out, float* __restrict__ val_out)
{
  __shared__ float tile[64][132];
  int t0 = blockIdx.x * 64;
  int z = blockIdx.y;
  int pl = plp[0];
  int tid = threadIdx.x;
  int cb = z < 16 ? z * 128 : (z < 24 ? 2048 + (z - 16) * 128 : 3072 + (z - 24) * 128);

  // load 64x128 tile = P0+P1 (rows stride 4096)
  {
    int r = tid >> 5;
    int c = (tid & 31) * 4;
#pragma unroll
    for (int i = 0; i < 8; ++i) {
      int row = i * 8 + r;
      size_t off = (size_t)(t0 + row) * 4096 + cb + c;
      fvec4 v = *(const fvec4*)(p0 + off) + *(const fvec4*)(p1 + off);
      *(fvec4*)&tile[row][c] = v;
    }
  }
  __syncthreads();

  if (z < 24) {
    // ---- RMS + RoPE: 4 threads per row, 32 d each ----
    int row = tid >> 2, q = tid & 3;
    int dbase = q * 32, pbase = (q ^ 2) * 32;
    const float* wn = z < 16 ? wq : wk;
    float sgn = (q < 2) ? -1.f : 1.f;
    fvec4 xv[8];
    float ss = 0.f;
#pragma unroll
    for (int j = 0; j < 8; ++j) {
      xv[j] = *(const fvec4*)&tile[row][dbase + j * 4];
      ss += xv[j][0]*xv[j][0] + xv[j][1]*xv[j][1] + xv[j][2]*xv[j][2] + xv[j][3]*xv[j][3];
    }
    ss += __shfl_xor(ss, 1);
    ss += __shfl_xor(ss, 2);
    float inv = rsqrtf(ss * (1.f / 128.f) + EPS_);
    int p = pl + t0 + row;
    float rv[32];
#pragma unroll
    for (int j = 0; j < 8; ++j) {
      fvec4 xo = *(const fvec4*)&tile[row][pbase + j * 4];
      fvec4 wv = *(const fvec4*)(wn + dbase + j * 4);
      fvec4 wo = *(const fvec4*)(wn + pbase + j * 4);
      fvec4 cs = *(const fvec4*)(cosT + (size_t)p * 128 + dbase + j * 4);
      fvec4 sn = *(const fvec4*)(sinT + (size_t)p * 128 + dbase + j * 4);
#pragma unroll
      for (int e = 0; e < 4; ++e) {
        float xn = wv[e] * xv[j][e] * inv;
        float xp = wo[e] * xo[e] * inv;
        rv[j * 4 + e] = xn * cs[e] + sgn * xp * sn[e];
      }
    }
    // write qr / kr (bf16, coalesced) — full 32 elements
    union { u32 w[8]; uint4 q4[2]; } ob;
    u16* orow = (z < 16 ? qr + ((size_t)z * T_ + t0 + row) * 128
                        : kr + ((size_t)(z - 16) * T_ + t0 + row) * 128) + dbase;
#pragma unroll
    for (int j = 0; j < 8; ++j)
      ob.w[j] = (u32)f2bf(rv[2 * j]) | ((u32)f2bf(rv[2 * j + 1]) << 16);
    *(uint4*)orow = ob.q4[0];
    *(uint4*)(orow + 8) = ob.q4[1];
#pragma unroll
    for (int j = 0; j < 8; ++j)
      ob.w[j] = (u32)f2bf(rv[16 + 2 * j]) | ((u32)f2bf(rv[17 + 2 * j]) << 16);
    *(uint4*)(orow + 16) = ob.q4[0];
    *(uint4*)(orow + 24) = ob.q4[1];

    if (z >= 16) {
      // write rotated values back, then transpose to key_out [d][p]
      __syncthreads();
#pragma unroll
      for (int j = 0; j < 8; ++j) {
        fvec4 v; v[0] = rv[j*4]; v[1] = rv[j*4+1]; v[2] = rv[j*4+2]; v[3] = rv[j*4+3];
        *(fvec4*)&tile[row][dbase + j * 4] = v;
      }
      __syncthreads();
      int d = tid >> 1, cc = (tid & 1) * 32;
      float* kp = key_out + ((size_t)(z - 16) * 128 + d) * SMAX_ + pl + t0 + cc;
      if ((pl & 3) == 0) {
#pragma unroll
        for (int j4 = 0; j4 < 8; ++j4) {
          fvec4 v;
#pragma unroll
          for (int e = 0; e < 4; ++e) v[e] = tile[cc + j4 * 4 + e][d];
          *(fvec4*)(kp + j4 * 4) = v;
        }
      } else {
        for (int j = 0; j < 32; ++j) kp[j] = tile[cc + j][d];
      }
    }
  } else {
    // ---- V: val_out direct (row-major) + vT transpose (bf16) ----
    int kv = z - 24;
    int row = tid >> 2, q = tid & 3;
    float* vp = val_out + ((size_t)kv * SMAX_ + pl + t0 + row) * 128 + q * 32;
#pragma unroll
    for (int j = 0; j < 8; ++j)
      *(fvec4*)(vp + j * 4) = *(const fvec4*)&tile[row][q * 32 + j * 4];
    // R5 BUG FIX: pack the FULL 32-element t-range (was 16 -> half of vT stale)
    int d = tid >> 1, cc = (tid & 1) * 32;
    union { u32 w[16]; uint4 q4[4]; } ob;
    u16* tp = vT + ((size_t)kv * 128 + d) * T_ + t0 + cc;
#pragma unroll
    for (int j = 0; j < 16; ++j)
      ob.w[j] = (u32)f2bf(tile[cc + 2 * j][d]) | ((u32)f2bf(tile[cc + 2 * j + 1][d]) << 16);
    *(uint4*)tp = ob.q4[0];
    *(uint4*)(tp + 8) = ob.q4[1];
    *(uint4*)(tp + 16) = ob.q4[2];
    *(uint4*)(tp + 24) = ob.q4[3];
  }
}

// ---------------- flash attention: QB=32, waves split s-range 2x2 ------------
__global__ __launch_bounds__(256)
void flash_k(const u16* __restrict__ qr, const u16* __restrict__ kr,
             const u16* __restrict__ vTb, const float* __restrict__ am,
             const int* __restrict__ plp, u16* __restrict__ ctx)
{
  __shared__ u16 lQ[QB * DH_];    // 8 KB
  __shared__ u16 lKV[SB * DH_];   // 32 KB (K tile, then V tile)
  __shared__ u16 lP[QB * SB];     // 8 KB
  __shared__ float lMax[2][2][16];
  __shared__ float lSum[2][2][16];
  __shared__ float lScale[QB];
  __shared__ float lFin[QB];

  int qt = gridDim.x - 1 - blockIdx.x;   // heavy diagonal blocks first
  int h = blockIdx.y;
  int kvh = h >> 1;
  int pl = plp[0];
  int tid = threadIdx.x;
  int l = tid & 63, w = tid >> 6;
  int lrow = l & 15, lk = l >> 4;
  int tb = w & 1, sh = w >> 1;           // t-block (16 cols), s-half (64 rows)
  int tcol = tb * 16 + lrow;

  const u16* Qb = qr + ((size_t)h * T_ + qt * QB) * DH_;
  const u16* Kb = kr + (size_t)kvh * T_ * DH_;
  const u16* Vb = vTb + (size_t)kvh * DH_ * T_;

  // stage Q (32 x 128): 512 16B units
#pragma unroll
  for (int r = 0; r < 2; ++r) {
    int c = r * 256 + tid;
    int row = c >> 4, g = c & 15;
    gld16(Qb + (size_t)row * DH_ + ((g ^ (row & 7)) << 3), (char*)lQ + c * 16);
  }

  float m_run = -3.0e38f, l_run = 0.f;
  f32x4 acc_o[2][2] = {};   // t-frag m (2), d-frag n (2, wave d-slice w*32)

  int t_lo = qt * QB;
  int s_hi = min(T_, t_lo + QB + pl);
  int nt = (s_hi + SB - 1) / SB;
  int tg = t_lo + tcol;

  for (int it = 0; it < nt; ++it) {
    int s0 = it * SB;
#pragma unroll
    for (int r = 0; r < 8; ++r) {
      int c = r * 256 + tid;
      int row = c >> 4, g = c & 15;
      gld16(Kb + (size_t)(s0 + row) * DH_ + ((g ^ (row & 7)) << 3), (char*)lKV + c * 16);
    }
    __syncthreads();   // B1: K (and Q) staged

    // S^T: wave computes s-rows [sh*64, +64), t-cols [tb*16, +16)
    f32x4 acc_s[4] = {};
#pragma unroll
    for (int kk = 0; kk < 4; ++kk) {
      int kbyte = kk * 64 + lk * 16;
      int trow = tb * 16 + lrow;
      bf16x8 bq = *(const bf16x8*)((const char*)lQ + ((trow * 256 + kbyte) ^ ((trow & 7) << 4)));
#pragma unroll
      for (int m = 0; m < 4; ++m) {
        int srow = sh * 64 + m * 16 + lrow;
        bf16x8 ak = *(const bf16x8*)((const char*)lKV + ((srow * 256 + kbyte) ^ ((srow & 7) << 4)));
        acc_s[m] = __builtin_amdgcn_mfma_f32_16x16x32_bf16(ak, bq, acc_s[m], 0, 0, 0);
      }
    }
    __syncthreads();   // B2: all waves done reading K

    // stage V tile (128 d-rows x 128 s-cols) into lKV
#pragma unroll
    for (int r = 0; r < 8; ++r) {
      int c = r * 256 + tid;
      int row = c >> 4, g = c & 15;
      gld16(Vb + (size_t)row * T_ + s0 + ((g ^ (row & 7)) << 3), (char*)lKV + c * 16);
    }

    // mask + local max over this wave's 16 s-values per t-col
    bool full = (s0 + SB <= t_lo + pl + 1);
    float sv[4][4];
    float vmax = -3.0e38f;
    if (full) {
#pragma unroll
      for (int m = 0; m < 4; ++m)
#pragma unroll
        for (int r = 0; r < 4; ++r) {
          float val = acc_s[m][r]; sv[m][r] = val; vmax = fmaxf(vmax, val);
        }
    } else {
#pragma unroll
      for (int m = 0; m < 4; ++m) {
        int sg = s0 + sh * 64 + m * 16 + lk * 4;
        fvec4 a4 = *(const fvec4*)(am + (size_t)tg * T_ + sg);
#pragma unroll
        for (int r = 0; r < 4; ++r) {
          float val = acc_s[m][r] + ((sg + r <= tg + pl) ? 0.f : -128.f * a4[r]);
          sv[m][r] = val; vmax = fmaxf(vmax, val);
        }
      }
    }
    vmax = fmaxf(vmax, __shfl_xor(vmax, 16));
    vmax = fmaxf(vmax, __shfl_xor(vmax, 32));
    if (lk == 0) lMax[tb][sh][lrow] = vmax;
    __syncthreads();   // B3: cross-wave max visible

    float om = fmaxf(lMax[tb][0][lrow], lMax[tb][1][lrow]);
    float m_new = fmaxf(m_run, om);
    float corr = __expf(m_run - m_new);
    float psum = 0.f;
    u32 pw[4][2];
#pragma unroll
    for (int m = 0; m < 4; ++m) {
      float p0 = __expf(sv[m][0] - m_new);
      float p1 = __expf(sv[m][1] - m_new);
      float p2 = __expf(sv[m][2] - m_new);
      float p3 = __expf(sv[m][3] - m_new);
      psum += (p0 + p1) + (p2 + p3);
      pw[m][0] = (u32)f2bf(p0) | ((u32)f2bf(p1) << 16);
      pw[m][1] = (u32)f2bf(p2) | ((u32)f2bf(p3) << 16);
    }
    psum += __shfl_xor(psum, 16);
    psum += __shfl_xor(psum, 32);
    if (lk == 0) lSum[tb][sh][lrow] = psum;
    if (lk == 0 && sh == 0) lScale[tcol] = corr;
    // write P[t][s-local]: this wave's s-half
#pragma unroll
    for (int m = 0; m < 4; ++m) {
      int byt = (tcol * 256 + sh * 128 + m * 32 + lk * 8) ^ ((tcol & 7) << 4);
      *(uint2*)((char*)lP + byt) = make_uint2(pw[m][0], pw[m][1]);
    }
    __syncthreads();   // B4: P/sums/scale visible + V landed

    l_run = l_run * corr + lSum[tb][0][lrow] + lSum[tb][1][lrow];
    m_run = m_new;
    // rescale acc_o rows t = m*16 + lk*4 + r
#pragma unroll
    for (int m = 0; m < 2; ++m) {
      fvec4 c4 = *(const fvec4*)&lScale[m * 16 + lk * 4];
#pragma unroll
      for (int n = 0; n < 2; ++n)
#pragma unroll
        for (int r = 0; r < 4; ++r) acc_o[m][n][r] *= c4[r];
    }
    // PV: C[t][d] += P(t,s) . V^T(d,s); wave d-slice w*32
#pragma unroll
    for (int kk = 0; kk < 4; ++kk) {
      int kbyte = kk * 64 + lk * 16;
      bf16x8 ap[2], bv[2];
#pragma unroll
      for (int m = 0; m < 2; ++m) {
        int trow = m * 16 + lrow;
        ap[m] = *(const bf16x8*)((const char*)lP + ((trow * 256 + kbyte) ^ ((trow & 7) << 4)));
      }
#pragma unroll
      for (int n = 0; n < 2; ++n) {
        int drow = w * 32 + n * 16 + lrow;
        bv[n] = *(const bf16x8*)((const char*)lKV + ((drow * 256 + kbyte) ^ ((drow & 7) << 4)));
      }
#pragma unroll
      for (int m = 0; m < 2; ++m)
#pragma unroll
        for (int n = 0; n < 2; ++n)
          acc_o[m][n] = __builtin_amdgcn_mfma_f32_16x16x32_bf16(ap[m], bv[n], acc_o[m][n], 0, 0, 0);
    }
    __syncthreads();   // B5: P/V reads done before next K stage
  }

  if (lk == 0 && sh == 0) lFin[tcol] = l_run;
  __syncthreads();
#pragma unroll
  for (int m = 0; m < 2; ++m) {
    fvec4 s4 = *(const fvec4*)&lFin[m * 16 + lk * 4];
#pragma unroll
    for (int r = 0; r < 4; ++r) {
      float inv = 1.f / s4[r];
      int trow = t_lo + m * 16 + lk * 4 + r;
      u16* crow = ctx + (size_t)trow * (H_ * DH_) + h * DH_;
#pragma unroll
      for (int n = 0; n < 2; ++n) {
        int d = w * 32 + n * 16 + lrow;
        crow[d] = f2bf(acc_o[m][n][r] * inv);
      }
    }
  }
}

// ---------------- final RMS (last token) + 4-partial combine -----------------
__global__ void frms_k(const float* __restrict__ x, const float* __restrict__ p,
                       const float* __restrict__ w, float* __restrict__ out)
{
  __shared__ float sm[4];
  float s = 0.f;
  for (int d = threadIdx.x; d < D_; d += 256) {
    float v = x[d] + p[d] + p[ZSE + d] + p[2 * ZSE + d] + p[3 * ZSE + d];
    s += v * v;
  }
  s = blk_sum(s, sm);
  float inv = rsqrtf(s * (1.f / D_) + EPS_);
  for (int d = threadIdx.x; d < D_; d += 256)
    out[d] = w[d] * (x[d] + p[d] + p[ZSE + d] + p[2 * ZSE + d] + p[3 * ZSE + d]) * inv;
}

// ---------------- LM head partial GEMV (f32) ---------------------------------
__global__ void lmgemv_k(const float* __restrict__ last, const float* __restrict__ Wlm,
                         float* __restrict__ part)
{
  __shared__ float ls[256];
  int v = blockIdx.x * 256 + threadIdx.x;
  int c = blockIdx.y;
  ls[threadIdx.x] = last[c * 256 + threadIdx.x];
  __syncthreads();
  const float* Wp = Wlm + (size_t)c * 256 * V_ + v;
  float acc = 0.f;
#pragma unroll 8
  for (int d = 0; d < 256; d++) acc += ls[d] * Wp[(size_t)d * V_];
  part[(size_t)c * V_ + v] = acc;
}

__global__ void amax_part_k(const float* __restrict__ part, float2* __restrict__ out)
{
  __shared__ float sv[4];
  __shared__ int si[4];
  int v = blockIdx.x * 256 + threadIdx.x;
  float val = 0.f;
#pragma unroll
  for (int c = 0; c < 8; c++) val += part[(size_t)c * V_ + v];
  float bv = val; int bi = v;
#pragma unroll
  for (int m = 32; m; m >>= 1) {
    float ov = __shfl_xor(bv, m);
    int oi = __shfl_xor(bi, m);
    if (ov > bv || (ov == bv && oi < bi)) { bv = ov; bi = oi; }
  }
  if ((threadIdx.x & 63) == 0) { sv[threadIdx.x >> 6] = bv; si[threadIdx.x >> 6] = bi; }
  __syncthreads();
  if (threadIdx.x == 0) {
    for (int w = 1; w < 4; w++)
      if (sv[w] > bv || (sv[w] == bv && si[w] < bi)) { bv = sv[w]; bi = si[w]; }
    out[blockIdx.x] = make_float2(bv, (float)bi);
  }
}

__global__ void finalize_k(const float2* __restrict__ part, int np,
                           const int* __restrict__ plp, float* __restrict__ dout,
                           unsigned long long lastoff)
{
  if (threadIdx.x == 0) {
    float bv = part[0].x; int bi = (int)part[0].y;
    for (int b = 1; b < np; b++) {
      float v = part[b].x; int i = (int)part[b].y;
      if (v > bv || (v == bv && i < bi)) { bv = v; bi = i; }
    }
    dout[0] = (float)bi;
    dout[lastoff] = (float)(plp[0] + T_);
  }
}

// =============================================================================
extern "C" void kernel_launch(void* const* d_in, const int* in_sizes, int n_in,
                              void* d_out, int out_size, void* d_ws, size_t ws_size,
                              hipStream_t stream)
{
  (void)in_sizes; (void)n_in; (void)out_size; (void)ws_size;

  const float* key_in  = (const float*)d_in[0];
  const float* val_in  = (const float*)d_in[1];
  const int*   ids     = (const int*)d_in[2];
  const float* am      = (const float*)d_in[3];
  const int*   plp     = (const int*)d_in[4];
  const void*  edata   = d_in[5];
  const float* esc     = (const float*)d_in[6];
  const float* ez      = (const float*)d_in[7];
  const float* cosT    = (const float*)d_in[8];
  const float* sinT    = (const float*)d_in[9];
  const float* w_in_ln = (const float*)d_in[10];
  const float* Wq      = (const float*)d_in[11];
  const float* Wk      = (const float*)d_in[12];
  const float* Wv      = (const float*)d_in[13];
  const float* wqn     = (const float*)d_in[14];
  const float* wkn     = (const float*)d_in[15];
  const float* Wo      = (const float*)d_in[16];
  const float* wpost   = (const float*)d_in[17];
  const float* Wg      = (const float*)d_in[18];
  const float* Wu      = (const float*)d_in[19];
  const float* Wd      = (const float*)d_in[20];
  const float* wfin    = (const float*)d_in[21];
  const float* Wlm     = (const float*)d_in[22];

  float* out = (float*)d_out;
  const size_t KVN = (size_t)L_ * KVH_ * DH_ * SMAX_; // 8388608
  float* key_out = out + 1;
  float* val_out = out + 1 + KVN;
  unsigned long long lastoff = 1 + 2 * KVN;

  char* ws = (char*)d_ws;
  u16*   wT     = (u16*)  (ws + 0);            // 50,331,648
  u16*   hn     = (u16*)  (ws + 50331648);     //  4,194,304
  float* P      = (float*)(ws + 54525952);     // 67,108,864 (4 split-K planes)
  u16*   qr     = (u16*)  (ws + 121634816);    //  4,194,304
  u16*   kr     = (u16*)  (ws + 125829120);    //  2,097,152
  u16*   vT     = (u16*)  (ws + 127926272);    //  2,097,152
  u16*   ctx    = (u16*)  (ws + 130023424);    //  4,194,304
  float* hidden = (float*)(ws + 134217728);    //  8,388,608
  u16*   mlp    = (u16*)  (ws + 142606336);    // 12,582,912
  float* last   = (float*)(ws + 155189248);    //      8,192
  float* lpart  = (float*)(ws + 155197440);    //  1,024,000
  float2* amaxp = (float2*)(ws + 156221440);   //      4,096

  hipMemcpyAsync(key_out, key_in, KVN * sizeof(float), hipMemcpyDeviceToDevice, stream);
  hipMemcpyAsync(val_out, val_in, KVN * sizeof(float), hipMemcpyDeviceToDevice, stream);
  embed_k<<<T_, 256, 0, stream>>>(ids, edata, esc, ez, hidden);

  for (int i = 0; i < L_; i++) {
    // --- attention ---
    if (i == 0)
      rms_k<0><<<T_ / 4, 256, 0, stream>>>(hidden, nullptr, w_in_ln, hn);
    else
      rms_k<4><<<T_ / 4, 256, 0, stream>>>(hidden, P, w_in_ln + (size_t)i * D_, hn);

    convT2_k<<<dim3(64, 32), 256, 0, stream>>>(
        Wq + (size_t)i * 4194304, Wk + (size_t)i * 2097152, Wv + (size_t)i * 2097152,
        32, 48, 2048, 1024, 1024, 0, 2048, 3072, 2048, wT, 0);
    gemm_bt<0><<<dim3(32, 8, 2), 256, 0, stream>>>(hn, wT, P, nullptr, 2048, 1024, 4096, ZSE);

    qkvpost_k<<<dim3(T_ / 64, 32), 256, 0, stream>>>(P, P + ZSE,
        wqn + (size_t)i * DH_, wkn + (size_t)i * DH_, cosT, sinT, plp,
        qr, kr, vT,
        key_out + (size_t)i * KVH_ * DH_ * SMAX_,
        val_out + (size_t)i * KVH_ * SMAX_ * DH_);

    flash_k<<<dim3(T_ / QB, H_), 256, 0, stream>>>(qr, kr, vT, am, plp, ctx);

    convT2_k<<<dim3(32, 32), 256, 0, stream>>>(
        Wo + (size_t)i * 4194304, nullptr, nullptr,
        32, 64, 2048, 2048, 2048, 0, 0, 0, 2048, wT, 0);
    gemm_bt<0><<<dim3(16, 8, 4), 256, 0, stream>>>(ctx, wT, P, nullptr, 2048, 512, 2048, ZSE);

    // --- MLP ---
    rms_k<4><<<T_ / 4, 256, 0, stream>>>(hidden, P, wpost + (size_t)i * D_, hn);

    convT2_k<<<dim3(192, 32), 256, 0, stream>>>(
        Wg + (size_t)i * 12582912, Wu + (size_t)i * 12582912, Wu + (size_t)i * 12582912,
        96, 192, 6144, 6144, 6144, 0, 16, 16, 2048, wT, 1);
    gemm_bt<3><<<dim3(96, 8, 1), 256, 0, stream>>>(hn, wT, nullptr, mlp, 2048, 2048, 6144, 0);

    convT2_k<<<dim3(32, 96), 256, 0, stream>>>(
        Wd + (size_t)i * 12582912, nullptr, nullptr,
        32, 64, 2048, 2048, 2048, 0, 0, 0, 6144, wT, 0);
    gemm_bt<0><<<dim3(16, 8, 4), 256, 0, stream>>>(mlp, wT, P, nullptr, 6144, 1536, 2048, ZSE);
  }

  frms_k<<<1, 256, 0, stream>>>(hidden + (size_t)(T_ - 1) * D_,
                                P + (size_t)(T_ - 1) * D_, wfin, last);
  lmgemv_k<<<dim3(V_ / 256, 8), 256, 0, stream>>>(last, Wlm, lpart);
  amax_part_k<<<V_ / 256, 256, 0, stream>>>(lpart, amaxp);
  finalize_k<<<1, 64, 0, stream>>>(amaxp, V_ / 256, plp, out, lastoff);
}

// Round 7
// 1133.170 us; speedup vs baseline: 1.0596x; 1.0596x over previous
//
#include <hip/hip_runtime.h>
#include <cstdint>

#define L_ 4
#define D_ 2048
#define H_ 16
#define KVH_ 8
#define DH_ 128
#define F_ 6144
#define V_ 32000
#define SMAX_ 2048
#define T_ 1024
#define EPS_ 1e-6f
#define QB 32
#define SB 128
#define ZSE 4194304  // u16 elements between split-K partial planes (8 MB)

typedef unsigned short u16;
typedef unsigned int u32;
typedef float fvec4 __attribute__((ext_vector_type(4)));
typedef float f32x4 __attribute__((ext_vector_type(4)));
typedef __bf16 bf16x8 __attribute__((ext_vector_type(8)));

__device__ __forceinline__ u16 f2bf(float f) {
  union { float f; u32 u; } a; a.f = f;
  u32 u = a.u;
  return (u16)((u + 0x7FFFu + ((u >> 16) & 1u)) >> 16);
}
__device__ __forceinline__ float bf2f(u16 h) {
  union { u32 u; float f; } a; a.u = (u32)h << 16; return a.f;
}
__device__ __forceinline__ fvec4 bf4(uint2 u) {
  union { u32 i; float f; } a, b, c, d;
  a.i = u.x << 16; b.i = u.x & 0xFFFF0000u;
  c.i = u.y << 16; d.i = u.y & 0xFFFF0000u;
  fvec4 r; r[0] = a.f; r[1] = b.f; r[2] = c.f; r[3] = d.f; return r;
}

__device__ __forceinline__ void gld16(const void* g, void* l) {
  __builtin_amdgcn_global_load_lds(
      (const __attribute__((address_space(1))) void*)g,
      (__attribute__((address_space(3))) void*)l, 16, 0, 0);
}

// ---------------- embedding (uint8-vs-int32 runtime detection) ---------------
__global__ void embed_k(const int* __restrict__ ids, const void* __restrict__ edata,
                        const float* __restrict__ esc, const float* __restrict__ ez,
                        float* __restrict__ hidden)
{
  const int* ei = (const int*)edata;
  int chk = ei[threadIdx.x & 63];
  bool ok = ((unsigned)chk) <= 255u;
  bool is_i32 = (__ballot(ok) == ~0ULL);
  int t = blockIdx.x;
  int id = ids[t];
  float sc = esc[id], zp = ez[id];
  size_t base = (size_t)id * D_;
  const uint8_t* eb = (const uint8_t*)edata;
  for (int d = threadIdx.x; d < D_; d += 256) {
    float e = is_i32 ? (float)ei[base + d] : (float)eb[base + d];
    hidden[(size_t)t * D_ + d] = e * sc + zp;
  }
}

// ------ convT body: W f32 (K,N) 64x64 tile -> WT bf16 (N,K) ------------------
// tile: 64*65 f32 scratch. gu=1: row = rb + ((f>>4)<<5) + (f&15)
__device__ __forceinline__ void convT_body(const float* __restrict__ W, int N,
                                           int nb, int kb, int K, int rb,
                                           u16* __restrict__ WT, int gu, float* tile)
{
  int n0 = nb * 64, k0 = kb * 64;
  int tid = threadIdx.x;
  int lk = tid >> 4, n4 = (tid & 15) * 4;
#pragma unroll
  for (int i = 0; i < 4; ++i) {
    int kr = i * 16 + lk;
    fvec4 v = *(const fvec4*)(W + (size_t)(k0 + kr) * N + n0 + n4);
#pragma unroll
    for (int j = 0; j < 4; ++j) tile[(n4 + j) * 65 + kr] = v[j];
  }
  __syncthreads();
  int n = tid >> 2, kq = (tid & 3) * 16;
  int f = n0 + n;
  int row = gu ? (rb + ((f >> 4) << 5) + (f & 15)) : (rb + f);
  union { u16 h[16]; uint4 q[2]; } o;
#pragma unroll
  for (int i = 0; i < 16; ++i) o.h[i] = f2bf(tile[n * 65 + kq + i]);
  u16* op = WT + (size_t)row * K + k0 + kq;
  *(uint4*)op = o.q[0];
  *(uint4*)(op + 8) = o.q[1];
}

// ------ RMS body: one wave per row; NZ: x += sum of NZ bf16 partial planes ---
template<int NZ>
__device__ __forceinline__ void rms_body(int idx, float* __restrict__ x,
                                         const u16* __restrict__ p,
                                         const float* __restrict__ w,
                                         u16* __restrict__ out)
{
  int t = idx * 4 + (threadIdx.x >> 6);
  int l = threadIdx.x & 63;
  fvec4* xr = (fvec4*)(x + (size_t)t * D_);
  fvec4 v[8];
#pragma unroll
  for (int j = 0; j < 8; ++j) v[j] = xr[l + 64 * j];
  if (NZ > 0) {
#pragma unroll
    for (int z = 0; z < NZ; ++z) {
      const uint2* a = (const uint2*)(p + (size_t)z * ZSE + (size_t)t * D_);
#pragma unroll
      for (int j = 0; j < 8; ++j) v[j] += bf4(a[l + 64 * j]);
    }
#pragma unroll
    for (int j = 0; j < 8; ++j) xr[l + 64 * j] = v[j];
  }
  float s = 0.f;
#pragma unroll
  for (int j = 0; j < 8; ++j)
    s += v[j][0]*v[j][0] + v[j][1]*v[j][1] + v[j][2]*v[j][2] + v[j][3]*v[j][3];
#pragma unroll
  for (int m = 32; m; m >>= 1) s += __shfl_xor(s, m);
  float inv = rsqrtf(s * (1.f / D_) + EPS_);
  const fvec4* wr = (const fvec4*)w;
  u16* orow = out + (size_t)t * D_;
#pragma unroll
  for (int j = 0; j < 8; ++j) {
    fvec4 wv = wr[l + 64 * j];
    uint2 o;
    o.x = (u32)f2bf(wv[0]*v[j][0]*inv) | ((u32)f2bf(wv[1]*v[j][1]*inv) << 16);
    o.y = (u32)f2bf(wv[2]*v[j][2]*inv) | ((u32)f2bf(wv[3]*v[j][3]*inv) << 16);
    *(uint2*)(orow + (l + 64 * j) * 4) = o;
  }
}

// ------ merged: convT(Wq,Wk,Wv) + rms(input-LN) ------------------------------
template<int NZ>
__global__ __launch_bounds__(256)
void convqkv_rms_k(const float* __restrict__ Wq, const float* __restrict__ Wk,
                   const float* __restrict__ Wv, u16* __restrict__ WT,
                   float* __restrict__ x, const u16* __restrict__ p,
                   const float* __restrict__ w, u16* __restrict__ out)
{
  __shared__ float tile[64 * 65];
  int bx = blockIdx.x, y = blockIdx.y;
  if (bx < 64) {
    const float* W; int N, nb, rb;
    if (bx < 32)      { W = Wq; N = 2048; nb = bx;      rb = 0; }
    else if (bx < 48) { W = Wk; N = 1024; nb = bx - 32; rb = 2048; }
    else              { W = Wv; N = 1024; nb = bx - 48; rb = 3072; }
    convT_body(W, N, nb, y, 2048, rb, WT, 0, tile);
  } else {
    rms_body<NZ>((bx - 64) * 32 + y, x, p, w, out);
  }
}

// ------ merged: convT(Wg,Wu -> gu-interleave) + convT(Wd) + rms(post-LN) -----
__global__ __launch_bounds__(256)
void convgu_wd_rms_k(const float* __restrict__ Wg, const float* __restrict__ Wu,
                     u16* __restrict__ WTgu, const float* __restrict__ Wd,
                     u16* __restrict__ WTwd,
                     float* __restrict__ x, const u16* __restrict__ p,
                     const float* __restrict__ w, u16* __restrict__ out)
{
  __shared__ float tile[64 * 65];
  int bx = blockIdx.x, y = blockIdx.y;
  if (bx < 192) {
    const float* W; int nb, rb;
    if (bx < 96) { W = Wg; nb = bx;      rb = 0; }
    else         { W = Wu; nb = bx - 96; rb = 16; }
    convT_body(W, 6144, nb, y, 2048, rb, WTgu, 1, tile);
  } else if (bx < 288) {
    int xp = bx - 192;
    convT_body(Wd, 2048, xp & 31, ((xp >> 5) << 5) + y, 6144, 0, WTwd, 0, tile);
  } else {
    rms_body<4>((bx - 288) * 32 + y, x, p, w, out);
  }
}

// -------- GEMM: C(MxN)=A(MxK)*B^T(NxK) bf16, split-K via blockIdx.z ----------
// EPI 0: Cb[z]=bf16(acc) (partial)  EPI 3: silu-pair -> Cb bf16
template<int EPI>
__global__ __launch_bounds__(256)
void gemm_bt(const u16* __restrict__ A, const u16* __restrict__ B,
             u16* __restrict__ Cb, int K, int Ks, int ldC, long long zStride)
{
  __shared__ u16 lA[128 * 64];
  __shared__ u16 lB[128 * 64];
  const u16* Ab = A + (size_t)blockIdx.y * 128 * K;
  const u16* Bb = B + (size_t)blockIdx.x * 128 * K;
  int kz = blockIdx.z * Ks;

  int tid = threadIdx.x;
  int l = tid & 63;
  int wid = tid >> 6;
  int wr = wid >> 1, wc = wid & 1;
  int lrow = l & 15, lk = l >> 4;

  f32x4 acc[4][4] = {};

  for (int k0 = 0; k0 < Ks; k0 += 64) {
#pragma unroll
    for (int r = 0; r < 4; ++r) {
      int c = r * 256 + tid;
      int row = c >> 3, g = c & 7;
      int kel = kz + k0 + ((g ^ (row & 7)) << 3);
      gld16(Ab + (size_t)row * K + kel, (char*)lA + c * 16);
      gld16(Bb + (size_t)row * K + kel, (char*)lB + c * 16);
    }
    __syncthreads();
#pragma unroll
    for (int kk = 0; kk < 2; ++kk) {
      bf16x8 av[4], bv[4];
      int kbyte = (kk * 32 + lk * 8) * 2;
#pragma unroll
      for (int m = 0; m < 4; ++m) {
        int row = wr * 64 + m * 16 + lrow;
        int byt = (row * 128 + kbyte) ^ ((row & 7) << 4);
        av[m] = *(const bf16x8*)((const char*)lA + byt);
      }
#pragma unroll
      for (int n = 0; n < 4; ++n) {
        int row = wc * 64 + n * 16 + lrow;
        int byt = (row * 128 + kbyte) ^ ((row & 7) << 4);
        bv[n] = *(const bf16x8*)((const char*)lB + byt);
      }
#pragma unroll
      for (int m = 0; m < 4; ++m)
#pragma unroll
        for (int n = 0; n < 4; ++n)
          acc[m][n] = __builtin_amdgcn_mfma_f32_16x16x32_bf16(av[m], bv[n], acc[m][n], 0, 0, 0);
    }
    __syncthreads();
  }

  int grow0 = blockIdx.y * 128 + wr * 64 + lk * 4;
  if (EPI == 3) {
    int fcol0 = blockIdx.x * 64 + wc * 32 + lrow;
#pragma unroll
    for (int m = 0; m < 4; ++m)
#pragma unroll
      for (int np = 0; np < 2; ++np)
#pragma unroll
        for (int r = 0; r < 4; ++r) {
          float g = acc[m][2 * np][r], u = acc[m][2 * np + 1][r];
          float val = g / (1.f + __expf(-g)) * u;
          Cb[(size_t)(grow0 + m * 16 + r) * ldC + fcol0 + np * 16] = f2bf(val);
        }
    return;
  }
  u16* Cz = Cb + (long long)blockIdx.z * zStride;
  int gcol0 = blockIdx.x * 128 + wc * 64 + lrow;
#pragma unroll
  for (int m = 0; m < 4; ++m)
#pragma unroll
    for (int n = 0; n < 4; ++n)
#pragma unroll
      for (int r = 0; r < 4; ++r)
        Cz[(size_t)(grow0 + m * 16 + r) * ldC + gcol0 + n * 16] = f2bf(acc[m][n][r]);
}

// ------ merged: QKV post-process (RMS+RoPE+KV stores) + convT(Wo) ------------
// x<16: qkvpost tile t0=x*64, z=y (z<16 Q | z<24 K | else V); x>=16: convT Wo
__global__ __launch_bounds__(256)
void qkvpost_convwo_k(const u16* __restrict__ p0, const u16* __restrict__ p1,
                      const float* __restrict__ wq, const float* __restrict__ wk,
                      const float* __restrict__ cosT, const float* __restrict__ sinT,
                      const int* __restrict__ plp,
                      u16* __restrict__ qr, u16* __restrict__ kr, u16* __restrict__ vT,
                      float* __restrict__ key_out, float* __restrict__ val_out,
                      const float* __restrict__ Wo, u16* __restrict__ WTo)
{
  __shared__ float tile[64][132];
  if (blockIdx.x >= 16) {
    convT_body(Wo, 2048, blockIdx.x - 16, blockIdx.y, 2048, 0, WTo, 0, &tile[0][0]);
    return;
  }
  int t0 = blockIdx.x * 64;
  int z = blockIdx.y;
  int pl = plp[0];
  int tid = threadIdx.x;
  int cb = z < 16 ? z * 128 : (z < 24 ? 2048 + (z - 16) * 128 : 3072 + (z - 24) * 128);

  // load 64x128 tile = bf16(P0)+bf16(P1) (rows stride 4096)
  {
    int r = tid >> 5;
    int c = (tid & 31) * 4;
#pragma unroll
    for (int i = 0; i < 8; ++i) {
      int row = i * 8 + r;
      size_t off = (size_t)(t0 + row) * 4096 + cb + c;
      fvec4 v = bf4(*(const uint2*)(p0 + off)) + bf4(*(const uint2*)(p1 + off));
      *(fvec4*)&tile[row][c] = v;
    }
  }
  __syncthreads();

  if (z < 24) {
    // ---- RMS + RoPE: 4 threads per row, 32 d each ----
    int row = tid >> 2, q = tid & 3;
    int dbase = q * 32, pbase = (q ^ 2) * 32;
    const float* wn = z < 16 ? wq : wk;
    float sgn = (q < 2) ? -1.f : 1.f;
    fvec4 xv[8];
    float ss = 0.f;
#pragma unroll
    for (int j = 0; j < 8; ++j) {
      xv[j] = *(const fvec4*)&tile[row][dbase + j * 4];
      ss += xv[j][0]*xv[j][0] + xv[j][1]*xv[j][1] + xv[j][2]*xv[j][2] + xv[j][3]*xv[j][3];
    }
    ss += __shfl_xor(ss, 1);
    ss += __shfl_xor(ss, 2);
    float inv = rsqrtf(ss * (1.f / 128.f) + EPS_);
    int p = pl + t0 + row;
    float rv[32];
#pragma unroll
    for (int j = 0; j < 8; ++j) {
      fvec4 xo = *(const fvec4*)&tile[row][pbase + j * 4];
      fvec4 wv = *(const fvec4*)(wn + dbase + j * 4);
      fvec4 wo = *(const fvec4*)(wn + pbase + j * 4);
      fvec4 cs = *(const fvec4*)(cosT + (size_t)p * 128 + dbase + j * 4);
      fvec4 sn = *(const fvec4*)(sinT + (size_t)p * 128 + dbase + j * 4);
#pragma unroll
      for (int e = 0; e < 4; ++e) {
        float xn = wv[e] * xv[j][e] * inv;
        float xp = wo[e] * xo[e] * inv;
        rv[j * 4 + e] = xn * cs[e] + sgn * xp * sn[e];
      }
    }
    // write qr / kr (bf16, coalesced) — full 32 elements
    union { u32 w[8]; uint4 q4[2]; } ob;
    u16* orow = (z < 16 ? qr + ((size_t)z * T_ + t0 + row) * 128
                        : kr + ((size_t)(z - 16) * T_ + t0 + row) * 128) + dbase;
#pragma unroll
    for (int j = 0; j < 8; ++j)
      ob.w[j] = (u32)f2bf(rv[2 * j]) | ((u32)f2bf(rv[2 * j + 1]) << 16);
    *(uint4*)orow = ob.q4[0];
    *(uint4*)(orow + 8) = ob.q4[1];
#pragma unroll
    for (int j = 0; j < 8; ++j)
      ob.w[j] = (u32)f2bf(rv[16 + 2 * j]) | ((u32)f2bf(rv[17 + 2 * j]) << 16);
    *(uint4*)(orow + 16) = ob.q4[0];
    *(uint4*)(orow + 24) = ob.q4[1];

    if (z >= 16) {
      // write rotated values back, then transpose to key_out [d][p]
      __syncthreads();
#pragma unroll
      for (int j = 0; j < 8; ++j) {
        fvec4 v; v[0] = rv[j*4]; v[1] = rv[j*4+1]; v[2] = rv[j*4+2]; v[3] = rv[j*4+3];
        *(fvec4*)&tile[row][dbase + j * 4] = v;
      }
      __syncthreads();
      int d = tid >> 1, cc = (tid & 1) * 32;
      float* kp = key_out + ((size_t)(z - 16) * 128 + d) * SMAX_ + pl + t0 + cc;
      if ((pl & 3) == 0) {
#pragma unroll
        for (int j4 = 0; j4 < 8; ++j4) {
          fvec4 v;
#pragma unroll
          for (int e = 0; e < 4; ++e) v[e] = tile[cc + j4 * 4 + e][d];
          *(fvec4*)(kp + j4 * 4) = v;
        }
      } else {
        for (int j = 0; j < 32; ++j) kp[j] = tile[cc + j][d];
      }
    }
  } else {
    // ---- V: val_out direct (row-major) + vT transpose (bf16, full 32) ----
    int kv = z - 24;
    int row = tid >> 2, q = tid & 3;
    float* vp = val_out + ((size_t)kv * SMAX_ + pl + t0 + row) * 128 + q * 32;
#pragma unroll
    for (int j = 0; j < 8; ++j)
      *(fvec4*)(vp + j * 4) = *(const fvec4*)&tile[row][q * 32 + j * 4];
    int d = tid >> 1, cc = (tid & 1) * 32;
    union { u32 w[16]; uint4 q4[4]; } ob;
    u16* tp = vT + ((size_t)kv * 128 + d) * T_ + t0 + cc;
#pragma unroll
    for (int j = 0; j < 16; ++j)
      ob.w[j] = (u32)f2bf(tile[cc + 2 * j][d]) | ((u32)f2bf(tile[cc + 2 * j + 1][d]) << 16);
    *(uint4*)tp = ob.q4[0];
    *(uint4*)(tp + 8) = ob.q4[1];
    *(uint4*)(tp + 16) = ob.q4[2];
    *(uint4*)(tp + 24) = ob.q4[3];
  }
}

// ---------------- flash attention: QB=32, waves split s-range 2x2 ------------
__global__ __launch_bounds__(256)
void flash_k(const u16* __restrict__ qr, const u16* __restrict__ kr,
             const u16* __restrict__ vTb, const float* __restrict__ am,
             const int* __restrict__ plp, u16* __restrict__ ctx)
{
  __shared__ u16 lQ[QB * DH_];
  __shared__ u16 lKV[SB * DH_];
  __shared__ u16 lP[QB * SB];
  __shared__ float lMax[2][2][16];
  __shared__ float lSum[2][2][16];
  __shared__ float lScale[QB];
  __shared__ float lFin[QB];

  int qt = gridDim.x - 1 - blockIdx.x;
  int h = blockIdx.y;
  int kvh = h >> 1;
  int pl = plp[0];
  int tid = threadIdx.x;
  int l = tid & 63, w = tid >> 6;
  int lrow = l & 15, lk = l >> 4;
  int tb = w & 1, sh = w >> 1;
  int tcol = tb * 16 + lrow;

  const u16* Qb = qr + ((size_t)h * T_ + qt * QB) * DH_;
  const u16* Kb = kr + (size_t)kvh * T_ * DH_;
  const u16* Vb = vTb + (size_t)kvh * DH_ * T_;

#pragma unroll
  for (int r = 0; r < 2; ++r) {
    int c = r * 256 + tid;
    int row = c >> 4, g = c & 15;
    gld16(Qb + (size_t)row * DH_ + ((g ^ (row & 7)) << 3), (char*)lQ + c * 16);
  }

  float m_run = -3.0e38f, l_run = 0.f;
  f32x4 acc_o[2][2] = {};

  int t_lo = qt * QB;
  int s_hi = min(T_, t_lo + QB + pl);
  int nt = (s_hi + SB - 1) / SB;
  int tg = t_lo + tcol;

  for (int it = 0; it < nt; ++it) {
    int s0 = it * SB;
#pragma unroll
    for (int r = 0; r < 8; ++r) {
      int c = r * 256 + tid;
      int row = c >> 4, g = c & 15;
      gld16(Kb + (size_t)(s0 + row) * DH_ + ((g ^ (row & 7)) << 3), (char*)lKV + c * 16);
    }
    __syncthreads();

    f32x4 acc_s[4] = {};
#pragma unroll
    for (int kk = 0; kk < 4; ++kk) {
      int kbyte = kk * 64 + lk * 16;
      int trow = tb * 16 + lrow;
      bf16x8 bq = *(const bf16x8*)((const char*)lQ + ((trow * 256 + kbyte) ^ ((trow & 7) << 4)));
#pragma unroll
      for (int m = 0; m < 4; ++m) {
        int srow = sh * 64 + m * 16 + lrow;
        bf16x8 ak = *(const bf16x8*)((const char*)lKV + ((srow * 256 + kbyte) ^ ((srow & 7) << 4)));
        acc_s[m] = __builtin_amdgcn_mfma_f32_16x16x32_bf16(ak, bq, acc_s[m], 0, 0, 0);
      }
    }
    __syncthreads();

#pragma unroll
    for (int r = 0; r < 8; ++r) {
      int c = r * 256 + tid;
      int row = c >> 4, g = c & 15;
      gld16(Vb + (size_t)row * T_ + s0 + ((g ^ (row & 7)) << 3), (char*)lKV + c * 16);
    }

    bool full = (s0 + SB <= t_lo + pl + 1);
    float sv[4][4];
    float vmax = -3.0e38f;
    if (full) {
#pragma unroll
      for (int m = 0; m < 4; ++m)
#pragma unroll
        for (int r = 0; r < 4; ++r) {
          float val = acc_s[m][r]; sv[m][r] = val; vmax = fmaxf(vmax, val);
        }
    } else {
#pragma unroll
      for (int m = 0; m < 4; ++m) {
        int sg = s0 + sh * 64 + m * 16 + lk * 4;
        fvec4 a4 = *(const fvec4*)(am + (size_t)tg * T_ + sg);
#pragma unroll
        for (int r = 0; r < 4; ++r) {
          float val = acc_s[m][r] + ((sg + r <= tg + pl) ? 0.f : -128.f * a4[r]);
          sv[m][r] = val; vmax = fmaxf(vmax, val);
        }
      }
    }
    vmax = fmaxf(vmax, __shfl_xor(vmax, 16));
    vmax = fmaxf(vmax, __shfl_xor(vmax, 32));
    if (lk == 0) lMax[tb][sh][lrow] = vmax;
    __syncthreads();

    float om = fmaxf(lMax[tb][0][lrow], lMax[tb][1][lrow]);
    float m_new = fmaxf(m_run, om);
    float corr = __expf(m_run - m_new);
    float psum = 0.f;
    u32 pw[4][2];
#pragma unroll
    for (int m = 0; m < 4; ++m) {
      float p0 = __expf(sv[m][0] - m_new);
      float p1 = __expf(sv[m][1] - m_new);
      float p2 = __expf(sv[m][2] - m_new);
      float p3 = __expf(sv[m][3] - m_new);
      psum += (p0 + p1) + (p2 + p3);
      pw[m][0] = (u32)f2bf(p0) | ((u32)f2bf(p1) << 16);
      pw[m][1] = (u32)f2bf(p2) | ((u32)f2bf(p3) << 16);
    }
    psum += __shfl_xor(psum, 16);
    psum += __shfl_xor(psum, 32);
    if (lk == 0) lSum[tb][sh][lrow] = psum;
    if (lk == 0 && sh == 0) lScale[tcol] = corr;
#pragma unroll
    for (int m = 0; m < 4; ++m) {
      int byt = (tcol * 256 + sh * 128 + m * 32 + lk * 8) ^ ((tcol & 7) << 4);
      *(uint2*)((char*)lP + byt) = make_uint2(pw[m][0], pw[m][1]);
    }
    __syncthreads();

    l_run = l_run * corr + lSum[tb][0][lrow] + lSum[tb][1][lrow];
    m_run = m_new;
#pragma unroll
    for (int m = 0; m < 2; ++m) {
      fvec4 c4 = *(const fvec4*)&lScale[m * 16 + lk * 4];
#pragma unroll
      for (int n = 0; n < 2; ++n)
#pragma unroll
        for (int r = 0; r < 4; ++r) acc_o[m][n][r] *= c4[r];
    }
#pragma unroll
    for (int kk = 0; kk < 4; ++kk) {
      int kbyte = kk * 64 + lk * 16;
      bf16x8 ap[2], bv[2];
#pragma unroll
      for (int m = 0; m < 2; ++m) {
        int trow = m * 16 + lrow;
        ap[m] = *(const bf16x8*)((const char*)lP + ((trow * 256 + kbyte) ^ ((trow & 7) << 4)));
      }
#pragma unroll
      for (int n = 0; n < 2; ++n) {
        int drow = w * 32 + n * 16 + lrow;
        bv[n] = *(const bf16x8*)((const char*)lKV + ((drow * 256 + kbyte) ^ ((drow & 7) << 4)));
      }
#pragma unroll
      for (int m = 0; m < 2; ++m)
#pragma unroll
        for (int n = 0; n < 2; ++n)
          acc_o[m][n] = __builtin_amdgcn_mfma_f32_16x16x32_bf16(ap[m], bv[n], acc_o[m][n], 0, 0, 0);
    }
    __syncthreads();
  }

  if (lk == 0 && sh == 0) lFin[tcol] = l_run;
  __syncthreads();
#pragma unroll
  for (int m = 0; m < 2; ++m) {
    fvec4 s4 = *(const fvec4*)&lFin[m * 16 + lk * 4];
#pragma unroll
    for (int r = 0; r < 4; ++r) {
      float inv = 1.f / s4[r];
      int trow = t_lo + m * 16 + lk * 4 + r;
      u16* crow = ctx + (size_t)trow * (H_ * DH_) + h * DH_;
#pragma unroll
      for (int n = 0; n < 2; ++n) {
        int d = w * 32 + n * 16 + lrow;
        crow[d] = f2bf(acc_o[m][n][r] * inv);
      }
    }
  }
}

// ---------------- final RMS (last token) + 4 bf16-partial combine ------------
__global__ void frms_k(const float* __restrict__ x, const u16* __restrict__ p,
                       const float* __restrict__ w, float* __restrict__ out)
{
  __shared__ float sm[4];
  float s = 0.f;
  for (int d = threadIdx.x; d < D_; d += 256) {
    float v = x[d] + bf2f(p[d]) + bf2f(p[ZSE + d]) + bf2f(p[2 * ZSE + d]) + bf2f(p[3 * ZSE + d]);
    s += v * v;
  }
#pragma unroll
  for (int m = 32; m; m >>= 1) s += __shfl_xor(s, m);
  if ((threadIdx.x & 63) == 0) sm[threadIdx.x >> 6] = s;
  __syncthreads();
  s = sm[0] + sm[1] + sm[2] + sm[3];
  float inv = rsqrtf(s * (1.f / D_) + EPS_);
  for (int d = threadIdx.x; d < D_; d += 256)
    out[d] = w[d] * (x[d] + bf2f(p[d]) + bf2f(p[ZSE + d]) + bf2f(p[2 * ZSE + d]) + bf2f(p[3 * ZSE + d])) * inv;
}

// ---------------- LM head partial GEMV (f32) ---------------------------------
__global__ void lmgemv_k(const float* __restrict__ last, const float* __restrict__ Wlm,
                         float* __restrict__ part)
{
  __shared__ float ls[256];
  int v = blockIdx.x * 256 + threadIdx.x;
  int c = blockIdx.y;
  ls[threadIdx.x] = last[c * 256 + threadIdx.x];
  __syncthreads();
  const float* Wp = Wlm + (size_t)c * 256 * V_ + v;
  float acc = 0.f;
#pragma unroll 8
  for (int d = 0; d < 256; d++) acc += ls[d] * Wp[(size_t)d * V_];
  part[(size_t)c * V_ + v] = acc;
}

__global__ void amax_part_k(const float* __restrict__ part, float2* __restrict__ out)
{
  __shared__ float sv[4];
  __shared__ int si[4];
  int v = blockIdx.x * 256 + threadIdx.x;
  float val = 0.f;
#pragma unroll
  for (int c = 0; c < 8; c++) val += part[(size_t)c * V_ + v];
  float bv = val; int bi = v;
#pragma unroll
  for (int m = 32; m; m >>= 1) {
    float ov = __shfl_xor(bv, m);
    int oi = __shfl_xor(bi, m);
    if (ov > bv || (ov == bv && oi < bi)) { bv = ov; bi = oi; }
  }
  if ((threadIdx.x & 63) == 0) { sv[threadIdx.x >> 6] = bv; si[threadIdx.x >> 6] = bi; }
  __syncthreads();
  if (threadIdx.x == 0) {
    for (int w = 1; w < 4; w++)
      if (sv[w] > bv || (sv[w] == bv && si[w] < bi)) { bv = sv[w]; bi = si[w]; }
    out[blockIdx.x] = make_float2(bv, (float)bi);
  }
}

__global__ void finalize_k(const float2* __restrict__ part, int np,
                           const int* __restrict__ plp, float* __restrict__ dout,
                           unsigned long long lastoff)
{
  if (threadIdx.x == 0) {
    float bv = part[0].x; int bi = (int)part[0].y;
    for (int b = 1; b < np; b++) {
      float v = part[b].x; int i = (int)part[b].y;
      if (v > bv || (v == bv && i < bi)) { bv = v; bi = i; }
    }
    dout[0] = (float)bi;
    dout[lastoff] = (float)(plp[0] + T_);
  }
}

// =============================================================================
extern "C" void kernel_launch(void* const* d_in, const int* in_sizes, int n_in,
                              void* d_out, int out_size, void* d_ws, size_t ws_size,
                              hipStream_t stream)
{
  (void)in_sizes; (void)n_in; (void)out_size; (void)ws_size;

  const float* key_in  = (const float*)d_in[0];
  const float* val_in  = (const float*)d_in[1];
  const int*   ids     = (const int*)d_in[2];
  const float* am      = (const float*)d_in[3];
  const int*   plp     = (const int*)d_in[4];
  const void*  edata   = d_in[5];
  const float* esc     = (const float*)d_in[6];
  const float* ez      = (const float*)d_in[7];
  const float* cosT    = (const float*)d_in[8];
  const float* sinT    = (const float*)d_in[9];
  const float* w_in_ln = (const float*)d_in[10];
  const float* Wq      = (const float*)d_in[11];
  const float* Wk      = (const float*)d_in[12];
  const float* Wv      = (const float*)d_in[13];
  const float* wqn     = (const float*)d_in[14];
  const float* wkn     = (const float*)d_in[15];
  const float* Wo      = (const float*)d_in[16];
  const float* wpost   = (const float*)d_in[17];
  const float* Wg      = (const float*)d_in[18];
  const float* Wu      = (const float*)d_in[19];
  const float* Wd      = (const float*)d_in[20];
  const float* wfin    = (const float*)d_in[21];
  const float* Wlm     = (const float*)d_in[22];

  float* out = (float*)d_out;
  const size_t KVN = (size_t)L_ * KVH_ * DH_ * SMAX_; // 8388608
  float* key_out = out + 1;
  float* val_out = out + 1 + KVN;
  unsigned long long lastoff = 1 + 2 * KVN;

  char* ws = (char*)d_ws;
  u16*   wT     = (u16*)  (ws + 0);            // 75,497,472 (GU 48M @0 + Wd 24M @48M; QKV/Wo reuse @0)
  u16*   wTwd   = wT + 25165824;               //   (offset 48 MB in u16 elems)
  u16*   hn     = (u16*)  (ws + 75497472);     //  4,194,304
  u16*   P      = (u16*)  (ws + 79691776);     // 33,554,432 (4 bf16 planes x 8 MB)
  u16*   qr     = (u16*)  (ws + 113246208);    //  4,194,304
  u16*   kr     = (u16*)  (ws + 117440512);    //  2,097,152
  u16*   vT     = (u16*)  (ws + 119537664);    //  2,097,152
  u16*   ctx    = (u16*)  (ws + 121634816);    //  4,194,304
  float* hidden = (float*)(ws + 125829120);    //  8,388,608
  u16*   mlp    = (u16*)  (ws + 134217728);    // 12,582,912
  float* last   = (float*)(ws + 146800640);    //      8,192
  float* lpart  = (float*)(ws + 146808832);    //  1,024,000
  float2* amaxp = (float2*)(ws + 147832832);   //      4,096

  hipMemcpyAsync(key_out, key_in, KVN * sizeof(float), hipMemcpyDeviceToDevice, stream);
  hipMemcpyAsync(val_out, val_in, KVN * sizeof(float), hipMemcpyDeviceToDevice, stream);
  embed_k<<<T_, 256, 0, stream>>>(ids, edata, esc, ez, hidden);

  for (int i = 0; i < L_; i++) {
    // --- attention: {convT QKV + input rms} -> QKV GEMM -> {qkvpost + convT Wo}
    if (i == 0)
      convqkv_rms_k<0><<<dim3(72, 32), 256, 0, stream>>>(
          Wq, Wk, Wv, wT, hidden, nullptr, w_in_ln, hn);
    else
      convqkv_rms_k<4><<<dim3(72, 32), 256, 0, stream>>>(
          Wq + (size_t)i * 4194304, Wk + (size_t)i * 2097152, Wv + (size_t)i * 2097152,
          wT, hidden, P, w_in_ln + (size_t)i * D_, hn);

    gemm_bt<0><<<dim3(32, 8, 2), 256, 0, stream>>>(hn, wT, P, 2048, 1024, 4096, ZSE);

    qkvpost_convwo_k<<<dim3(48, 32), 256, 0, stream>>>(P, P + ZSE,
        wqn + (size_t)i * DH_, wkn + (size_t)i * DH_, cosT, sinT, plp,
        qr, kr, vT,
        key_out + (size_t)i * KVH_ * DH_ * SMAX_,
        val_out + (size_t)i * KVH_ * SMAX_ * DH_,
        Wo + (size_t)i * 4194304, wT);

    flash_k<<<dim3(T_ / QB, H_), 256, 0, stream>>>(qr, kr, vT, am, plp, ctx);

    gemm_bt<0><<<dim3(16, 8, 4), 256, 0, stream>>>(ctx, wT, P, 2048, 512, 2048, ZSE);

    // --- MLP: {convT GU + convT Wd + post rms} -> GU GEMM(silu) -> Wd GEMM ---
    convgu_wd_rms_k<<<dim3(296, 32), 256, 0, stream>>>(
        Wg + (size_t)i * 12582912, Wu + (size_t)i * 12582912, wT,
        Wd + (size_t)i * 12582912, wTwd,
        hidden, P, wpost + (size_t)i * D_, hn);

    gemm_bt<3><<<dim3(96, 8, 1), 256, 0, stream>>>(hn, wT, mlp, 2048, 2048, 6144, 0);

    gemm_bt<0><<<dim3(16, 8, 4), 256, 0, stream>>>(mlp, wTwd, P, 6144, 1536, 2048, ZSE);
  }

  frms_k<<<1, 256, 0, stream>>>(hidden + (size_t)(T_ - 1) * D_,
                                P + (size_t)(T_ - 1) * D_, wfin, last);
  lmgemv_k<<<dim3(V_ / 256, 8), 256, 0, stream>>>(last, Wlm, lpart);
  amax_part_k<<<V_ / 256, 256, 0, stream>>>(lpart, amaxp);
  finalize_k<<<1, 64, 0, stream>>>(amaxp, V_ / 256, plp, out, lastoff);
}

// Round 8
// 1073.110 us; speedup vs baseline: 1.1189x; 1.0560x over previous
//
#include <hip/hip_runtime.h>
#include <cstdint>

#define L_ 4
#define D_ 2048
#define H_ 16
#define KVH_ 8
#define DH_ 128
#define F_ 6144
#define V_ 32000
#define SMAX_ 2048
#define T_ 1024
#define EPS_ 1e-6f
#define QB 32
#define SB 128
#define ZQK 4194304   // u16 stride between QKV partial planes (8 MB)
#define ZS2 2097152   // u16 stride between Wo/Wd partial planes (4 MB)

typedef unsigned short u16;
typedef unsigned int u32;
typedef float fvec4 __attribute__((ext_vector_type(4)));
typedef float f32x4 __attribute__((ext_vector_type(4)));
typedef __bf16 bf16x8 __attribute__((ext_vector_type(8)));

__device__ __forceinline__ u16 f2bf(float f) {
  union { float f; u32 u; } a; a.f = f;
  u32 u = a.u;
  return (u16)((u + 0x7FFFu + ((u >> 16) & 1u)) >> 16);
}
__device__ __forceinline__ float bf2f(u16 h) {
  union { u32 u; float f; } a; a.u = (u32)h << 16; return a.f;
}
__device__ __forceinline__ fvec4 bf4(uint2 u) {
  union { u32 i; float f; } a, b, c, d;
  a.i = u.x << 16; b.i = u.x & 0xFFFF0000u;
  c.i = u.y << 16; d.i = u.y & 0xFFFF0000u;
  fvec4 r; r[0] = a.f; r[1] = b.f; r[2] = c.f; r[3] = d.f; return r;
}

__device__ __forceinline__ void gld16(const void* g, void* l) {
  __builtin_amdgcn_global_load_lds(
      (const __attribute__((address_space(1))) void*)g,
      (__attribute__((address_space(3))) void*)l, 16, 0, 0);
}

// ---------------- embedding (uint8-vs-int32 runtime detection) ---------------
__global__ void embed_k(const int* __restrict__ ids, const void* __restrict__ edata,
                        const float* __restrict__ esc, const float* __restrict__ ez,
                        float* __restrict__ hidden)
{
  const int* ei = (const int*)edata;
  int chk = ei[threadIdx.x & 63];
  bool ok = ((unsigned)chk) <= 255u;
  bool is_i32 = (__ballot(ok) == ~0ULL);
  int t = blockIdx.x;
  int id = ids[t];
  float sc = esc[id], zp = ez[id];
  size_t base = (size_t)id * D_;
  const uint8_t* eb = (const uint8_t*)edata;
  for (int d = threadIdx.x; d < D_; d += 256) {
    float e = is_i32 ? (float)ei[base + d] : (float)eb[base + d];
    hidden[(size_t)t * D_ + d] = e * sc + zp;
  }
}

// ------ convT body: W f32 (K,N) 64x64 tile -> WT bf16 (N,K) ------------------
__device__ __forceinline__ void convT_body(const float* __restrict__ W, int N,
                                           int nb, int kb, int K, int rb,
                                           u16* __restrict__ WT, int gu, float* tile)
{
  int n0 = nb * 64, k0 = kb * 64;
  int tid = threadIdx.x;
  int lk = tid >> 4, n4 = (tid & 15) * 4;
#pragma unroll
  for (int i = 0; i < 4; ++i) {
    int kr = i * 16 + lk;
    fvec4 v = *(const fvec4*)(W + (size_t)(k0 + kr) * N + n0 + n4);
#pragma unroll
    for (int j = 0; j < 4; ++j) tile[(n4 + j) * 65 + kr] = v[j];
  }
  __syncthreads();
  int n = tid >> 2, kq = (tid & 3) * 16;
  int f = n0 + n;
  int row = gu ? (rb + ((f >> 4) << 5) + (f & 15)) : (rb + f);
  union { u16 h[16]; uint4 q[2]; } o;
#pragma unroll
  for (int i = 0; i < 16; ++i) o.h[i] = f2bf(tile[n * 65 + kq + i]);
  u16* op = WT + (size_t)row * K + k0 + kq;
  *(uint4*)op = o.q[0];
  *(uint4*)(op + 8) = o.q[1];
}

// ------ RMS body: one wave per row; NZ: x += sum of NZ bf16 partial planes ---
template<int NZ>
__device__ __forceinline__ void rms_body(int idx, float* __restrict__ x,
                                         const u16* __restrict__ p, int zs,
                                         const float* __restrict__ w,
                                         u16* __restrict__ out)
{
  int t = idx * 4 + (threadIdx.x >> 6);
  int l = threadIdx.x & 63;
  fvec4* xr = (fvec4*)(x + (size_t)t * D_);
  fvec4 v[8];
#pragma unroll
  for (int j = 0; j < 8; ++j) v[j] = xr[l + 64 * j];
  if (NZ > 0) {
#pragma unroll
    for (int z = 0; z < NZ; ++z) {
      const uint2* a = (const uint2*)(p + (size_t)z * zs + (size_t)t * D_);
#pragma unroll
      for (int j = 0; j < 8; ++j) v[j] += bf4(a[l + 64 * j]);
    }
#pragma unroll
    for (int j = 0; j < 8; ++j) xr[l + 64 * j] = v[j];
  }
  float s = 0.f;
#pragma unroll
  for (int j = 0; j < 8; ++j)
    s += v[j][0]*v[j][0] + v[j][1]*v[j][1] + v[j][2]*v[j][2] + v[j][3]*v[j][3];
#pragma unroll
  for (int m = 32; m; m >>= 1) s += __shfl_xor(s, m);
  float inv = rsqrtf(s * (1.f / D_) + EPS_);
  const fvec4* wr = (const fvec4*)w;
  u16* orow = out + (size_t)t * D_;
#pragma unroll
  for (int j = 0; j < 8; ++j) {
    fvec4 wv = wr[l + 64 * j];
    uint2 o;
    o.x = (u32)f2bf(wv[0]*v[j][0]*inv) | ((u32)f2bf(wv[1]*v[j][1]*inv) << 16);
    o.y = (u32)f2bf(wv[2]*v[j][2]*inv) | ((u32)f2bf(wv[3]*v[j][3]*inv) << 16);
    *(uint2*)(orow + (l + 64 * j) * 4) = o;
  }
}

// ------ merged: convT(Wq,Wk,Wv) + rms(input-LN) ------------------------------
template<int NZ>
__global__ __launch_bounds__(256)
void convqkv_rms_k(const float* __restrict__ Wq, const float* __restrict__ Wk,
                   const float* __restrict__ Wv, u16* __restrict__ WT,
                   float* __restrict__ x, const u16* __restrict__ p,
                   const float* __restrict__ w, u16* __restrict__ out)
{
  __shared__ float tile[64 * 65];
  int bx = blockIdx.x, y = blockIdx.y;
  if (bx < 64) {
    const float* W; int N, nb, rb;
    if (bx < 32)      { W = Wq; N = 2048; nb = bx;      rb = 0; }
    else if (bx < 48) { W = Wk; N = 1024; nb = bx - 32; rb = 2048; }
    else              { W = Wv; N = 1024; nb = bx - 48; rb = 3072; }
    convT_body(W, N, nb, y, 2048, rb, WT, 0, tile);
  } else {
    rms_body<NZ>((bx - 64) * 32 + y, x, p, ZS2, w, out);
  }
}

// ------ standalone RMS (post-LN), grid 256 -----------------------------------
__global__ __launch_bounds__(256)
void rms_k(float* __restrict__ x, const u16* __restrict__ p,
           const float* __restrict__ w, u16* __restrict__ out)
{
  rms_body<4>(blockIdx.x, x, p, ZS2, w, out);
}

// -------- GEMM body: C(MxN)=A(MxK)*B^T(NxK) bf16 -----------------------------
// EPI 0: Cb[z]=bf16(acc) (split-K partial)  EPI 3: silu-pair -> Cb bf16
template<int EPI>
__device__ __forceinline__ void gemm_body(const u16* __restrict__ A,
                                          const u16* __restrict__ B,
                                          u16* __restrict__ Cb,
                                          int K, int Ks, int ldC, long long zStride,
                                          int bx, int by, int bz, char* smem)
{
  u16* lA = (u16*)smem;
  u16* lB = (u16*)(smem + 16384);
  const u16* Ab = A + (size_t)by * 128 * K;
  const u16* Bb = B + (size_t)bx * 128 * K;
  int kz = bz * Ks;

  int tid = threadIdx.x;
  int l = tid & 63;
  int wid = tid >> 6;
  int wr = wid >> 1, wc = wid & 1;
  int lrow = l & 15, lk = l >> 4;

  f32x4 acc[4][4] = {};

  for (int k0 = 0; k0 < Ks; k0 += 64) {
#pragma unroll
    for (int r = 0; r < 4; ++r) {
      int c = r * 256 + tid;
      int row = c >> 3, g = c & 7;
      int kel = kz + k0 + ((g ^ (row & 7)) << 3);
      gld16(Ab + (size_t)row * K + kel, (char*)lA + c * 16);
      gld16(Bb + (size_t)row * K + kel, (char*)lB + c * 16);
    }
    __syncthreads();
#pragma unroll
    for (int kk = 0; kk < 2; ++kk) {
      bf16x8 av[4], bv[4];
      int kbyte = (kk * 32 + lk * 8) * 2;
#pragma unroll
      for (int m = 0; m < 4; ++m) {
        int row = wr * 64 + m * 16 + lrow;
        int byt = (row * 128 + kbyte) ^ ((row & 7) << 4);
        av[m] = *(const bf16x8*)((const char*)lA + byt);
      }
#pragma unroll
      for (int n = 0; n < 4; ++n) {
        int row = wc * 64 + n * 16 + lrow;
        int byt = (row * 128 + kbyte) ^ ((row & 7) << 4);
        bv[n] = *(const bf16x8*)((const char*)lB + byt);
      }
#pragma unroll
      for (int m = 0; m < 4; ++m)
#pragma unroll
        for (int n = 0; n < 4; ++n)
          acc[m][n] = __builtin_amdgcn_mfma_f32_16x16x32_bf16(av[m], bv[n], acc[m][n], 0, 0, 0);
    }
    __syncthreads();
  }

  int grow0 = by * 128 + wr * 64 + lk * 4;
  if (EPI == 3) {
    int fcol0 = bx * 64 + wc * 32 + lrow;
#pragma unroll
    for (int m = 0; m < 4; ++m)
#pragma unroll
      for (int np = 0; np < 2; ++np)
#pragma unroll
        for (int r = 0; r < 4; ++r) {
          float g = acc[m][2 * np][r], u = acc[m][2 * np + 1][r];
          float val = g / (1.f + __expf(-g)) * u;
          Cb[(size_t)(grow0 + m * 16 + r) * ldC + fcol0 + np * 16] = f2bf(val);
        }
    return;
  }
  u16* Cz = Cb + (long long)bz * zStride;
  int gcol0 = bx * 128 + wc * 64 + lrow;
#pragma unroll
  for (int m = 0; m < 4; ++m)
#pragma unroll
    for (int n = 0; n < 4; ++n)
#pragma unroll
      for (int r = 0; r < 4; ++r)
        Cz[(size_t)(grow0 + m * 16 + r) * ldC + gcol0 + n * 16] = f2bf(acc[m][n][r]);
}

template<int EPI>
__global__ __launch_bounds__(256)
void gemm_bt(const u16* __restrict__ A, const u16* __restrict__ B,
             u16* __restrict__ Cb, int K, int Ks, int ldC, long long zStride)
{
  __shared__ char smem[32768];
  gemm_body<EPI>(A, B, Cb, K, Ks, ldC, zStride, blockIdx.x, blockIdx.y, blockIdx.z, smem);
}

// ------ mega: QKV GEMM (512 blocks, first) + convT(Wo,Wg,Wu,Wd) --------------
__global__ __launch_bounds__(256)
void qkvgemm_conv_k(const u16* __restrict__ hn, const u16* __restrict__ wTqkv,
                    u16* __restrict__ P,
                    const float* __restrict__ Wo, u16* __restrict__ wTo,
                    const float* __restrict__ Wg, const float* __restrict__ Wu,
                    u16* __restrict__ wTgu,
                    const float* __restrict__ Wd, u16* __restrict__ wTwd)
{
  __shared__ char smem[32768];
  int bx = blockIdx.x;
  if (bx < 512) {
    gemm_body<0>(hn, wTqkv, P, 2048, 1024, 4096, ZQK,
                 bx & 31, (bx >> 5) & 7, bx >> 8, smem);
  } else if (bx < 1536) {
    int cb = bx - 512;
    convT_body(Wo, 2048, cb & 31, cb >> 5, 2048, 0, wTo, 0, (float*)smem);
  } else if (bx < 7680) {
    int cb = bx - 1536;
    int x = cb % 192, y = cb / 192;
    const float* W = x < 96 ? Wg : Wu;
    convT_body(W, 6144, x < 96 ? x : x - 96, y, 2048, x < 96 ? 0 : 16, wTgu, 1, (float*)smem);
  } else {
    int cb = bx - 7680;
    int xp = cb % 96, y = cb / 96;
    convT_body(Wd, 2048, xp & 31, ((xp >> 5) << 5) + y, 6144, 0, wTwd, 0, (float*)smem);
  }
}

// ------ QKV post-process (RMS+RoPE+KV stores), grid (16,32) ------------------
__global__ __launch_bounds__(256)
void qkvpost_k(const u16* __restrict__ p0, const u16* __restrict__ p1,
               const float* __restrict__ wq, const float* __restrict__ wk,
               const float* __restrict__ cosT, const float* __restrict__ sinT,
               const int* __restrict__ plp,
               u16* __restrict__ qr, u16* __restrict__ kr, u16* __restrict__ vT,
               float* __restrict__ key_out, float* __restrict__ val_out)
{
  __shared__ float tile[64][132];
  int t0 = blockIdx.x * 64;
  int z = blockIdx.y;
  int pl = plp[0];
  int tid = threadIdx.x;
  int cb = z < 16 ? z * 128 : (z < 24 ? 2048 + (z - 16) * 128 : 3072 + (z - 24) * 128);

  {
    int r = tid >> 5;
    int c = (tid & 31) * 4;
#pragma unroll
    for (int i = 0; i < 8; ++i) {
      int row = i * 8 + r;
      size_t off = (size_t)(t0 + row) * 4096 + cb + c;
      fvec4 v = bf4(*(const uint2*)(p0 + off)) + bf4(*(const uint2*)(p1 + off));
      *(fvec4*)&tile[row][c] = v;
    }
  }
  __syncthreads();

  if (z < 24) {
    int row = tid >> 2, q = tid & 3;
    int dbase = q * 32, pbase = (q ^ 2) * 32;
    const float* wn = z < 16 ? wq : wk;
    float sgn = (q < 2) ? -1.f : 1.f;
    fvec4 xv[8];
    float ss = 0.f;
#pragma unroll
    for (int j = 0; j < 8; ++j) {
      xv[j] = *(const fvec4*)&tile[row][dbase + j * 4];
      ss += xv[j][0]*xv[j][0] + xv[j][1]*xv[j][1] + xv[j][2]*xv[j][2] + xv[j][3]*xv[j][3];
    }
    ss += __shfl_xor(ss, 1);
    ss += __shfl_xor(ss, 2);
    float inv = rsqrtf(ss * (1.f / 128.f) + EPS_);
    int p = pl + t0 + row;
    float rv[32];
#pragma unroll
    for (int j = 0; j < 8; ++j) {
      fvec4 xo = *(const fvec4*)&tile[row][pbase + j * 4];
      fvec4 wv = *(const fvec4*)(wn + dbase + j * 4);
      fvec4 wo = *(const fvec4*)(wn + pbase + j * 4);
      fvec4 cs = *(const fvec4*)(cosT + (size_t)p * 128 + dbase + j * 4);
      fvec4 sn = *(const fvec4*)(sinT + (size_t)p * 128 + dbase + j * 4);
#pragma unroll
      for (int e = 0; e < 4; ++e) {
        float xn = wv[e] * xv[j][e] * inv;
        float xp = wo[e] * xo[e] * inv;
        rv[j * 4 + e] = xn * cs[e] + sgn * xp * sn[e];
      }
    }
    union { u32 w[8]; uint4 q4[2]; } ob;
    u16* orow = (z < 16 ? qr + ((size_t)z * T_ + t0 + row) * 128
                        : kr + ((size_t)(z - 16) * T_ + t0 + row) * 128) + dbase;
#pragma unroll
    for (int j = 0; j < 8; ++j)
      ob.w[j] = (u32)f2bf(rv[2 * j]) | ((u32)f2bf(rv[2 * j + 1]) << 16);
    *(uint4*)orow = ob.q4[0];
    *(uint4*)(orow + 8) = ob.q4[1];
#pragma unroll
    for (int j = 0; j < 8; ++j)
      ob.w[j] = (u32)f2bf(rv[16 + 2 * j]) | ((u32)f2bf(rv[17 + 2 * j]) << 16);
    *(uint4*)(orow + 16) = ob.q4[0];
    *(uint4*)(orow + 24) = ob.q4[1];

    if (z >= 16) {
      __syncthreads();
#pragma unroll
      for (int j = 0; j < 8; ++j) {
        fvec4 v; v[0] = rv[j*4]; v[1] = rv[j*4+1]; v[2] = rv[j*4+2]; v[3] = rv[j*4+3];
        *(fvec4*)&tile[row][dbase + j * 4] = v;
      }
      __syncthreads();
      int d = tid >> 1, cc = (tid & 1) * 32;
      float* kp = key_out + ((size_t)(z - 16) * 128 + d) * SMAX_ + pl + t0 + cc;
      if ((pl & 3) == 0) {
#pragma unroll
        for (int j4 = 0; j4 < 8; ++j4) {
          fvec4 v;
#pragma unroll
          for (int e = 0; e < 4; ++e) v[e] = tile[cc + j4 * 4 + e][d];
          *(fvec4*)(kp + j4 * 4) = v;
        }
      } else {
        for (int j = 0; j < 32; ++j) kp[j] = tile[cc + j][d];
      }
    }
  } else {
    int kv = z - 24;
    int row = tid >> 2, q = tid & 3;
    float* vp = val_out + ((size_t)kv * SMAX_ + pl + t0 + row) * 128 + q * 32;
#pragma unroll
    for (int j = 0; j < 8; ++j)
      *(fvec4*)(vp + j * 4) = *(const fvec4*)&tile[row][q * 32 + j * 4];
    int d = tid >> 1, cc = (tid & 1) * 32;
    union { u32 w[16]; uint4 q4[4]; } ob;
    u16* tp = vT + ((size_t)kv * 128 + d) * T_ + t0 + cc;
#pragma unroll
    for (int j = 0; j < 16; ++j)
      ob.w[j] = (u32)f2bf(tile[cc + 2 * j][d]) | ((u32)f2bf(tile[cc + 2 * j + 1][d]) << 16);
    *(uint4*)tp = ob.q4[0];
    *(uint4*)(tp + 8) = ob.q4[1];
    *(uint4*)(tp + 16) = ob.q4[2];
    *(uint4*)(tp + 24) = ob.q4[3];
  }
}

// ---------------- flash attention: QB=32, waves split s-range 2x2 ------------
__global__ __launch_bounds__(256)
void flash_k(const u16* __restrict__ qr, const u16* __restrict__ kr,
             const u16* __restrict__ vTb, const float* __restrict__ am,
             const int* __restrict__ plp, u16* __restrict__ ctx)
{
  __shared__ u16 lQ[QB * DH_];
  __shared__ u16 lKV[SB * DH_];
  __shared__ u16 lP[QB * SB];
  __shared__ float lMax[2][2][16];
  __shared__ float lSum[2][2][16];
  __shared__ float lScale[QB];
  __shared__ float lFin[QB];

  int qt = gridDim.x - 1 - blockIdx.x;
  int h = blockIdx.y;
  int kvh = h >> 1;
  int pl = plp[0];
  int tid = threadIdx.x;
  int l = tid & 63, w = tid >> 6;
  int lrow = l & 15, lk = l >> 4;
  int tb = w & 1, sh = w >> 1;
  int tcol = tb * 16 + lrow;

  const u16* Qb = qr + ((size_t)h * T_ + qt * QB) * DH_;
  const u16* Kb = kr + (size_t)kvh * T_ * DH_;
  const u16* Vb = vTb + (size_t)kvh * DH_ * T_;

#pragma unroll
  for (int r = 0; r < 2; ++r) {
    int c = r * 256 + tid;
    int row = c >> 4, g = c & 15;
    gld16(Qb + (size_t)row * DH_ + ((g ^ (row & 7)) << 3), (char*)lQ + c * 16);
  }

  float m_run = -3.0e38f, l_run = 0.f;
  f32x4 acc_o[2][2] = {};

  int t_lo = qt * QB;
  int s_hi = min(T_, t_lo + QB + pl);
  int nt = (s_hi + SB - 1) / SB;
  int tg = t_lo + tcol;

  for (int it = 0; it < nt; ++it) {
    int s0 = it * SB;
#pragma unroll
    for (int r = 0; r < 8; ++r) {
      int c = r * 256 + tid;
      int row = c >> 4, g = c & 15;
      gld16(Kb + (size_t)(s0 + row) * DH_ + ((g ^ (row & 7)) << 3), (char*)lKV + c * 16);
    }
    __syncthreads();

    f32x4 acc_s[4] = {};
#pragma unroll
    for (int kk = 0; kk < 4; ++kk) {
      int kbyte = kk * 64 + lk * 16;
      int trow = tb * 16 + lrow;
      bf16x8 bq = *(const bf16x8*)((const char*)lQ + ((trow * 256 + kbyte) ^ ((trow & 7) << 4)));
#pragma unroll
      for (int m = 0; m < 4; ++m) {
        int srow = sh * 64 + m * 16 + lrow;
        bf16x8 ak = *(const bf16x8*)((const char*)lKV + ((srow * 256 + kbyte) ^ ((srow & 7) << 4)));
        acc_s[m] = __builtin_amdgcn_mfma_f32_16x16x32_bf16(ak, bq, acc_s[m], 0, 0, 0);
      }
    }
    __syncthreads();

#pragma unroll
    for (int r = 0; r < 8; ++r) {
      int c = r * 256 + tid;
      int row = c >> 4, g = c & 15;
      gld16(Vb + (size_t)row * T_ + s0 + ((g ^ (row & 7)) << 3), (char*)lKV + c * 16);
    }

    bool full = (s0 + SB <= t_lo + pl + 1);
    float sv[4][4];
    float vmax = -3.0e38f;
    if (full) {
#pragma unroll
      for (int m = 0; m < 4; ++m)
#pragma unroll
        for (int r = 0; r < 4; ++r) {
          float val = acc_s[m][r]; sv[m][r] = val; vmax = fmaxf(vmax, val);
        }
    } else {
#pragma unroll
      for (int m = 0; m < 4; ++m) {
        int sg = s0 + sh * 64 + m * 16 + lk * 4;
        fvec4 a4 = *(const fvec4*)(am + (size_t)tg * T_ + sg);
#pragma unroll
        for (int r = 0; r < 4; ++r) {
          float val = acc_s[m][r] + ((sg + r <= tg + pl) ? 0.f : -128.f * a4[r]);
          sv[m][r] = val; vmax = fmaxf(vmax, val);
        }
      }
    }
    vmax = fmaxf(vmax, __shfl_xor(vmax, 16));
    vmax = fmaxf(vmax, __shfl_xor(vmax, 32));
    if (lk == 0) lMax[tb][sh][lrow] = vmax;
    __syncthreads();

    float om = fmaxf(lMax[tb][0][lrow], lMax[tb][1][lrow]);
    float m_new = fmaxf(m_run, om);
    float corr = __expf(m_run - m_new);
    float psum = 0.f;
    u32 pw[4][2];
#pragma unroll
    for (int m = 0; m < 4; ++m) {
      float p0 = __expf(sv[m][0] - m_new);
      float p1 = __expf(sv[m][1] - m_new);
      float p2 = __expf(sv[m][2] - m_new);
      float p3 = __expf(sv[m][3] - m_new);
      psum += (p0 + p1) + (p2 + p3);
      pw[m][0] = (u32)f2bf(p0) | ((u32)f2bf(p1) << 16);
      pw[m][1] = (u32)f2bf(p2) | ((u32)f2bf(p3) << 16);
    }
    psum += __shfl_xor(psum, 16);
    psum += __shfl_xor(psum, 32);
    if (lk == 0) lSum[tb][sh][lrow] = psum;
    if (lk == 0 && sh == 0) lScale[tcol] = corr;
#pragma unroll
    for (int m = 0; m < 4; ++m) {
      int byt = (tcol * 256 + sh * 128 + m * 32 + lk * 8) ^ ((tcol & 7) << 4);
      *(uint2*)((char*)lP + byt) = make_uint2(pw[m][0], pw[m][1]);
    }
    __syncthreads();

    l_run = l_run * corr + lSum[tb][0][lrow] + lSum[tb][1][lrow];
    m_run = m_new;
#pragma unroll
    for (int m = 0; m < 2; ++m) {
      fvec4 c4 = *(const fvec4*)&lScale[m * 16 + lk * 4];
#pragma unroll
      for (int n = 0; n < 2; ++n)
#pragma unroll
        for (int r = 0; r < 4; ++r) acc_o[m][n][r] *= c4[r];
    }
#pragma unroll
    for (int kk = 0; kk < 4; ++kk) {
      int kbyte = kk * 64 + lk * 16;
      bf16x8 ap[2], bv[2];
#pragma unroll
      for (int m = 0; m < 2; ++m) {
        int trow = m * 16 + lrow;
        ap[m] = *(const bf16x8*)((const char*)lP + ((trow * 256 + kbyte) ^ ((trow & 7) << 4)));
      }
#pragma unroll
      for (int n = 0; n < 2; ++n) {
        int drow = w * 32 + n * 16 + lrow;
        bv[n] = *(const bf16x8*)((const char*)lKV + ((drow * 256 + kbyte) ^ ((drow & 7) << 4)));
      }
#pragma unroll
      for (int m = 0; m < 2; ++m)
#pragma unroll
        for (int n = 0; n < 2; ++n)
          acc_o[m][n] = __builtin_amdgcn_mfma_f32_16x16x32_bf16(ap[m], bv[n], acc_o[m][n], 0, 0, 0);
    }
    __syncthreads();
  }

  if (lk == 0 && sh == 0) lFin[tcol] = l_run;
  __syncthreads();
#pragma unroll
  for (int m = 0; m < 2; ++m) {
    fvec4 s4 = *(const fvec4*)&lFin[m * 16 + lk * 4];
#pragma unroll
    for (int r = 0; r < 4; ++r) {
      float inv = 1.f / s4[r];
      int trow = t_lo + m * 16 + lk * 4 + r;
      u16* crow = ctx + (size_t)trow * (H_ * DH_) + h * DH_;
#pragma unroll
      for (int n = 0; n < 2; ++n) {
        int d = w * 32 + n * 16 + lrow;
        crow[d] = f2bf(acc_o[m][n][r] * inv);
      }
    }
  }
}

// ------ LM head GEMV with inlined final-RMS (x = hidden last row) ------------
__global__ void lmgemv_k(const float* __restrict__ x, const u16* __restrict__ p,
                         const float* __restrict__ wfin, const float* __restrict__ Wlm,
                         float* __restrict__ part)
{
  __shared__ float ls[256];
  __shared__ float sm[4];
  int tid = threadIdx.x;
  int c = blockIdx.y;
  float xv[8];
  float s = 0.f;
#pragma unroll
  for (int j = 0; j < 8; ++j) {
    int d = j * 256 + tid;
    float v = x[d] + bf2f(p[d]) + bf2f(p[ZS2 + d]) + bf2f(p[2 * ZS2 + d]) + bf2f(p[3 * ZS2 + d]);
    xv[j] = v; s += v * v;
  }
#pragma unroll
  for (int m = 32; m; m >>= 1) s += __shfl_xor(s, m);
  if ((tid & 63) == 0) sm[tid >> 6] = s;
  __syncthreads();
  s = sm[0] + sm[1] + sm[2] + sm[3];
  float inv = rsqrtf(s * (1.f / D_) + EPS_);
#pragma unroll
  for (int j = 0; j < 8; ++j)
    if (j == c) ls[tid] = wfin[j * 256 + tid] * xv[j] * inv;
  __syncthreads();
  int v = blockIdx.x * 256 + tid;
  const float* Wp = Wlm + (size_t)c * 256 * V_ + v;
  float acc = 0.f;
#pragma unroll 8
  for (int d = 0; d < 256; d++) acc += ls[d] * Wp[(size_t)d * V_];
  part[(size_t)c * V_ + v] = acc;
}

__global__ void amax_part_k(const float* __restrict__ part, float2* __restrict__ out)
{
  __shared__ float sv[4];
  __shared__ int si[4];
  int v = blockIdx.x * 256 + threadIdx.x;
  float val = 0.f;
#pragma unroll
  for (int c = 0; c < 8; c++) val += part[(size_t)c * V_ + v];
  float bv = val; int bi = v;
#pragma unroll
  for (int m = 32; m; m >>= 1) {
    float ov = __shfl_xor(bv, m);
    int oi = __shfl_xor(bi, m);
    if (ov > bv || (ov == bv && oi < bi)) { bv = ov; bi = oi; }
  }
  if ((threadIdx.x & 63) == 0) { sv[threadIdx.x >> 6] = bv; si[threadIdx.x >> 6] = bi; }
  __syncthreads();
  if (threadIdx.x == 0) {
    for (int w = 1; w < 4; w++)
      if (sv[w] > bv || (sv[w] == bv && si[w] < bi)) { bv = sv[w]; bi = si[w]; }
    out[blockIdx.x] = make_float2(bv, (float)bi);
  }
}

__global__ void finalize_k(const float2* __restrict__ part, int np,
                           const int* __restrict__ plp, float* __restrict__ dout,
                           unsigned long long lastoff)
{
  if (threadIdx.x == 0) {
    float bv = part[0].x; int bi = (int)part[0].y;
    for (int b = 1; b < np; b++) {
      float v = part[b].x; int i = (int)part[b].y;
      if (v > bv || (v == bv && i < bi)) { bv = v; bi = i; }
    }
    dout[0] = (float)bi;
    dout[lastoff] = (float)(plp[0] + T_);
  }
}

// =============================================================================
extern "C" void kernel_launch(void* const* d_in, const int* in_sizes, int n_in,
                              void* d_out, int out_size, void* d_ws, size_t ws_size,
                              hipStream_t stream)
{
  (void)in_sizes; (void)n_in; (void)out_size; (void)ws_size;

  const float* key_in  = (const float*)d_in[0];
  const float* val_in  = (const float*)d_in[1];
  const int*   ids     = (const int*)d_in[2];
  const float* am      = (const float*)d_in[3];
  const int*   plp     = (const int*)d_in[4];
  const void*  edata   = d_in[5];
  const float* esc     = (const float*)d_in[6];
  const float* ez      = (const float*)d_in[7];
  const float* cosT    = (const float*)d_in[8];
  const float* sinT    = (const float*)d_in[9];
  const float* w_in_ln = (const float*)d_in[10];
  const float* Wq      = (const float*)d_in[11];
  const float* Wk      = (const float*)d_in[12];
  const float* Wv      = (const float*)d_in[13];
  const float* wqn     = (const float*)d_in[14];
  const float* wkn     = (const float*)d_in[15];
  const float* Wo      = (const float*)d_in[16];
  const float* wpost   = (const float*)d_in[17];
  const float* Wg      = (const float*)d_in[18];
  const float* Wu      = (const float*)d_in[19];
  const float* Wd      = (const float*)d_in[20];
  const float* wfin    = (const float*)d_in[21];
  const float* Wlm     = (const float*)d_in[22];

  float* out = (float*)d_out;
  const size_t KVN = (size_t)L_ * KVH_ * DH_ * SMAX_; // 8388608
  float* key_out = out + 1;
  float* val_out = out + 1 + KVN;
  unsigned long long lastoff = 1 + 2 * KVN;

  char* ws = (char*)d_ws;
  u16*   wTqkv  = (u16*)  (ws + 0);            // 32 MB (k1 write, k2 read)
  u16*   mlp    = (u16*)  (ws + 0);            // 12.6 MB alias (k7 write, k8 read)
  float* lpart  = (float*)(ws + 16777216);     // 1 MB alias (end of run)
  float2* amaxp = (float2*)(ws + 17825792);
  u16*   wTo    = (u16*)  (ws + 33554432);     //  8 MB
  u16*   wTgu   = (u16*)  (ws + 41943040);     // 48 MB
  u16*   wTwd   = (u16*)  (ws + 92274688);     // 24 MB
  u16*   P      = (u16*)  (ws + 117440512);    // 16 MB (QKV 2x8MB | Wo/Wd 4x4MB)
  u16*   hn     = (u16*)  (ws + 134217728);    //  4 MB
  u16*   qr     = (u16*)  (ws + 138412032);    //  4 MB
  u16*   kr     = (u16*)  (ws + 142606336);    //  2 MB
  u16*   vT     = (u16*)  (ws + 144703488);    //  2 MB
  u16*   ctx    = (u16*)  (ws + 146800640);    //  4 MB
  float* hidden = (float*)(ws + 150994944);    //  8 MB  (end 159,383,552 < R1-proven 168.8 MB)

  hipMemcpyAsync(key_out, key_in, KVN * sizeof(float), hipMemcpyDeviceToDevice, stream);
  hipMemcpyAsync(val_out, val_in, KVN * sizeof(float), hipMemcpyDeviceToDevice, stream);
  embed_k<<<T_, 256, 0, stream>>>(ids, edata, esc, ez, hidden);

  for (int i = 0; i < L_; i++) {
    // k1: convT(QKV) + input RMS (reads Wd partials of prev layer)
    if (i == 0)
      convqkv_rms_k<0><<<dim3(72, 32), 256, 0, stream>>>(
          Wq, Wk, Wv, wTqkv, hidden, nullptr, w_in_ln, hn);
    else
      convqkv_rms_k<4><<<dim3(72, 32), 256, 0, stream>>>(
          Wq + (size_t)i * 4194304, Wk + (size_t)i * 2097152, Wv + (size_t)i * 2097152,
          wTqkv, hidden, P, w_in_ln + (size_t)i * D_, hn);

    // k2: QKV GEMM + convT(Wo, Wg, Wu, Wd) mega-kernel
    qkvgemm_conv_k<<<10752, 256, 0, stream>>>(
        hn, wTqkv, P,
        Wo + (size_t)i * 4194304, wTo,
        Wg + (size_t)i * 12582912, Wu + (size_t)i * 12582912, wTgu,
        Wd + (size_t)i * 12582912, wTwd);

    // k3: QKV post-process
    qkvpost_k<<<dim3(16, 32), 256, 0, stream>>>(P, P + ZQK,
        wqn + (size_t)i * DH_, wkn + (size_t)i * DH_, cosT, sinT, plp,
        qr, kr, vT,
        key_out + (size_t)i * KVH_ * DH_ * SMAX_,
        val_out + (size_t)i * KVH_ * SMAX_ * DH_);

    // k4: flash attention
    flash_k<<<dim3(T_ / QB, H_), 256, 0, stream>>>(qr, kr, vT, am, plp, ctx);

    // k5: Wo GEMM (split-K z=4, 4 MB planes)
    gemm_bt<0><<<dim3(16, 8, 4), 256, 0, stream>>>(ctx, wTo, P, 2048, 512, 2048, ZS2);

    // k6: post RMS (combines Wo partials into hidden)
    rms_k<<<256, 256, 0, stream>>>(hidden, P, wpost + (size_t)i * D_, hn);

    // k7: GU GEMM with fused silu -> mlp (bf16)
    gemm_bt<3><<<dim3(96, 8, 1), 256, 0, stream>>>(hn, wTgu, mlp, 2048, 2048, 6144, 0);

    // k8: Wd GEMM (split-K z=4)
    gemm_bt<0><<<dim3(16, 8, 4), 256, 0, stream>>>(mlp, wTwd, P, 6144, 1536, 2048, ZS2);
  }

  lmgemv_k<<<dim3(V_ / 256, 8), 256, 0, stream>>>(
      hidden + (size_t)(T_ - 1) * D_, P + (size_t)(T_ - 1) * D_, wfin, Wlm, lpart);
  amax_part_k<<<V_ / 256, 256, 0, stream>>>(lpart, amaxp);
  finalize_k<<<1, 64, 0, stream>>>(amaxp, V_ / 256, plp, out, lastoff);
}